// Round 1
// baseline (4636.010 us; speedup 1.0000x reference)
//
#include <hip/hip_runtime.h>

typedef unsigned int u32;
typedef unsigned long long u64;

#define C_DIM 1024
#define B_ROWS 8192
#define N_EMB 8192
#define BN_EPS_C 1e-5f

// ---------------- deterministic block reduce (256 threads) ----------------
__device__ __forceinline__ float block_reduce_sum_256(float v) {
#pragma unroll
  for (int off = 32; off > 0; off >>= 1) v += __shfl_xor(v, off, 64);
  __shared__ float sh[4];
  __syncthreads();
  const int lane = threadIdx.x & 63, w = threadIdx.x >> 6;
  if (lane == 0) sh[w] = v;
  __syncthreads();
  return (sh[0] + sh[1]) + (sh[2] + sh[3]);
}

__device__ __forceinline__ u64 shfl_xor_u64_16(u64 v, int m) {
  int lo = __shfl_xor((int)(u32)v, m, 16);
  int hi = __shfl_xor((int)(u32)(v >> 32), m, 16);
  return ((u64)(u32)hi << 32) | (u32)lo;
}

// ---------------- row L2 normalize (+ sum-of-squares of normalized row) ----
__global__ __launch_bounds__(256) void l2norm_rows(const float* __restrict__ in,
                                                   float* __restrict__ out,
                                                   float* __restrict__ ssq) {
  const int row = blockIdx.x;
  const float4 v = ((const float4*)(in + (size_t)row * C_DIM))[threadIdx.x];
  float ss = v.x * v.x + v.y * v.y + v.z * v.z + v.w * v.w;
  ss = block_reduce_sum_256(ss);
  float nrm = sqrtf(ss);
  nrm = fmaxf(nrm, 1e-12f);  // jnp.clip(norm, 1e-12, None)
  float4 o;
  o.x = v.x / nrm; o.y = v.y / nrm; o.z = v.z / nrm; o.w = v.w / nrm;
  ((float4*)(out + (size_t)row * C_DIM))[threadIdx.x] = o;
  float s2 = o.x * o.x + o.y * o.y + o.z * o.z + o.w * o.w;
  s2 = block_reduce_sum_256(s2);
  if (threadIdx.x == 0) ssq[row] = s2;
}

// ---------------- fused NT GEMM: out[i][j] = sum_k A[i][k]*W[j][k] ----------
// MODE 0: +bias, store.  MODE 1: +bias, tanh, store.
// MODE 2: distance argmin epilogue (bias == |e_k|^2 array, uses zz/best).
template <int MODE>
__global__ __launch_bounds__(256) void gemm_nt(
    const float* __restrict__ A, const float* __restrict__ W,
    const float* __restrict__ bias, float* __restrict__ out,
    const float* __restrict__ zz, u64* __restrict__ best, int M, int N, int K) {
  __shared__ float As[16][128];
  __shared__ float Bs[16][128];
  const int tid = threadIdx.x;
  const int tx = tid & 15, ty = tid >> 4;
  const int m0 = blockIdx.y * 128, n0 = blockIdx.x * 128;
  const int lrow = tid >> 2;
  const int lkq = (tid & 3) << 2;

  const float* aPtr = A + (size_t)(m0 + lrow) * K + lkq;
  const float* bPtr = W + (size_t)(n0 + lrow) * K + lkq;
  const size_t rowStride = (size_t)64 * K;

  float acc[2][2][4][4];
#pragma unroll
  for (int p = 0; p < 2; ++p)
#pragma unroll
    for (int q = 0; q < 2; ++q)
#pragma unroll
      for (int i = 0; i < 4; ++i)
#pragma unroll
        for (int j = 0; j < 4; ++j) acc[p][q][i][j] = 0.f;

  for (int k0 = 0; k0 < K; k0 += 16) {
    const float4 a0 = *(const float4*)(aPtr + k0);
    const float4 a1 = *(const float4*)(aPtr + rowStride + k0);
    const float4 b0 = *(const float4*)(bPtr + k0);
    const float4 b1 = *(const float4*)(bPtr + rowStride + k0);
    __syncthreads();
    As[lkq + 0][lrow] = a0.x; As[lkq + 1][lrow] = a0.y;
    As[lkq + 2][lrow] = a0.z; As[lkq + 3][lrow] = a0.w;
    As[lkq + 0][lrow + 64] = a1.x; As[lkq + 1][lrow + 64] = a1.y;
    As[lkq + 2][lrow + 64] = a1.z; As[lkq + 3][lrow + 64] = a1.w;
    Bs[lkq + 0][lrow] = b0.x; Bs[lkq + 1][lrow] = b0.y;
    Bs[lkq + 2][lrow] = b0.z; Bs[lkq + 3][lrow] = b0.w;
    Bs[lkq + 0][lrow + 64] = b1.x; Bs[lkq + 1][lrow + 64] = b1.y;
    Bs[lkq + 2][lrow + 64] = b1.z; Bs[lkq + 3][lrow + 64] = b1.w;
    __syncthreads();

    // two-level accumulation: per-16-k local sum folded into master acc
    float accl[2][2][4][4];
#pragma unroll
    for (int p = 0; p < 2; ++p)
#pragma unroll
      for (int q = 0; q < 2; ++q)
#pragma unroll
        for (int i = 0; i < 4; ++i)
#pragma unroll
          for (int j = 0; j < 4; ++j) accl[p][q][i][j] = 0.f;

#pragma unroll
    for (int k = 0; k < 16; ++k) {
      float ar[2][4], br[2][4];
      *(float4*)&ar[0][0] = *(const float4*)&As[k][ty * 4];
      *(float4*)&ar[1][0] = *(const float4*)&As[k][ty * 4 + 64];
      *(float4*)&br[0][0] = *(const float4*)&Bs[k][tx * 4];
      *(float4*)&br[1][0] = *(const float4*)&Bs[k][tx * 4 + 64];
#pragma unroll
      for (int p = 0; p < 2; ++p)
#pragma unroll
        for (int q = 0; q < 2; ++q)
#pragma unroll
          for (int i = 0; i < 4; ++i)
#pragma unroll
            for (int j = 0; j < 4; ++j) accl[p][q][i][j] += ar[p][i] * br[q][j];
    }
#pragma unroll
    for (int p = 0; p < 2; ++p)
#pragma unroll
      for (int q = 0; q < 2; ++q)
#pragma unroll
        for (int i = 0; i < 4; ++i)
#pragma unroll
          for (int j = 0; j < 4; ++j) acc[p][q][i][j] += accl[p][q][i][j];
  }

  if (MODE == 2) {
    float s4[2][4];
    *(float4*)&s4[0][0] = *(const float4*)(bias + n0 + tx * 4);
    *(float4*)&s4[1][0] = *(const float4*)(bias + n0 + 64 + tx * 4);
#pragma unroll
    for (int p = 0; p < 2; ++p)
#pragma unroll
      for (int i = 0; i < 4; ++i) {
        const int row = m0 + p * 64 + ty * 4 + i;
        const float zr = zz[row];
        u64 bkey = ~0ull;
#pragma unroll
        for (int q = 0; q < 2; ++q)
#pragma unroll
          for (int j = 0; j < 4; ++j) {
            // replicate reference association: (zz + s_e) - 2*dot
            const float d = (zr + s4[q][j]) - 2.0f * acc[p][q][i][j];
            const u32 fb = __float_as_uint(d);
            const u32 k32 = (fb & 0x80000000u) ? ~fb : (fb | 0x80000000u);
            const u64 key =
                ((u64)k32 << 32) | (u32)(n0 + q * 64 + tx * 4 + j);
            bkey = (key < bkey) ? key : bkey;
          }
#pragma unroll
        for (int mm = 1; mm < 16; mm <<= 1) {
          const u64 o = shfl_xor_u64_16(bkey, mm);
          bkey = (o < bkey) ? o : bkey;
        }
        if (tx == 0) atomicMin(best + row, bkey);
      }
  } else {
    float bb[2][4];
    *(float4*)&bb[0][0] = *(const float4*)(bias + n0 + tx * 4);
    *(float4*)&bb[1][0] = *(const float4*)(bias + n0 + 64 + tx * 4);
#pragma unroll
    for (int p = 0; p < 2; ++p)
#pragma unroll
      for (int i = 0; i < 4; ++i) {
        const int row = m0 + p * 64 + ty * 4 + i;
#pragma unroll
        for (int q = 0; q < 2; ++q) {
          float4 r;
          r.x = acc[p][q][i][0] + bb[q][0];
          r.y = acc[p][q][i][1] + bb[q][1];
          r.z = acc[p][q][i][2] + bb[q][2];
          r.w = acc[p][q][i][3] + bb[q][3];
          if (MODE == 1) {
            r.x = tanhf(r.x); r.y = tanhf(r.y);
            r.z = tanhf(r.z); r.w = tanhf(r.w);
          }
          *(float4*)(out + (size_t)row * N + n0 + q * 64 + tx * 4) = r;
        }
      }
  }
}

// ---------------- BatchNorm batch-stats (deterministic two-stage) -----------
__global__ __launch_bounds__(256) void bn_stats1(const float* __restrict__ t,
                                                 float* __restrict__ p1,
                                                 float* __restrict__ p2) {
  const int tx = threadIdx.x & 63, ty = threadIdx.x >> 6;
  const int c = blockIdx.x * 64 + tx;
  const int r0 = blockIdx.y * 512;
  float s = 0.f, ss = 0.f;
  for (int i = ty; i < 512; i += 4) {
    const float v = t[(size_t)(r0 + i) * C_DIM + c];
    s += v;
    ss += v * v;
  }
  __shared__ float sh1[4][64], sh2[4][64];
  sh1[ty][tx] = s;
  sh2[ty][tx] = ss;
  __syncthreads();
  if (ty == 0) {
    s = (sh1[0][tx] + sh1[1][tx]) + (sh1[2][tx] + sh1[3][tx]);
    ss = (sh2[0][tx] + sh2[1][tx]) + (sh2[2][tx] + sh2[3][tx]);
    p1[blockIdx.y * C_DIM + c] = s;
    p2[blockIdx.y * C_DIM + c] = ss;
  }
}

__global__ __launch_bounds__(256) void bn_stats2(const float* __restrict__ p1,
                                                 const float* __restrict__ p2,
                                                 const float* __restrict__ g,
                                                 float* __restrict__ mean,
                                                 float* __restrict__ scale) {
  const int c = blockIdx.x * 256 + threadIdx.x;
  float s = 0.f, ss = 0.f;
  for (int i = 0; i < 16; ++i) {
    s += p1[i * C_DIM + c];
    ss += p2[i * C_DIM + c];
  }
  const float m = s * (1.0f / 8192.0f);
  const float v = ss * (1.0f / 8192.0f) - m * m;  // biased var
  mean[c] = m;
  scale[c] = g[c] / sqrtf(v + BN_EPS_C);
}

__global__ __launch_bounds__(256) void bn_relu_apply(
    const float* __restrict__ t, const float* __restrict__ mean,
    const float* __restrict__ scale, const float* __restrict__ be,
    float* __restrict__ out) {
  const int i = blockIdx.x * 256 + threadIdx.x;
  const int c4 = i & 255;
  const float4 v = ((const float4*)t)[i];
  const float4 m = ((const float4*)mean)[c4];
  const float4 sc = ((const float4*)scale)[c4];
  const float4 b = ((const float4*)be)[c4];
  float4 r;
  r.x = fmaxf((v.x - m.x) * sc.x + b.x, 0.f);
  r.y = fmaxf((v.y - m.y) * sc.y + b.y, 0.f);
  r.z = fmaxf((v.z - m.z) * sc.z + b.z, 0.f);
  r.w = fmaxf((v.w - m.w) * sc.w + b.w, 0.f);
  ((float4*)out)[i] = r;
}

// ---------------- VQ pieces -------------------------------------------------
__global__ __launch_bounds__(256) void init_best(u64* __restrict__ best) {
  best[blockIdx.x * 256 + threadIdx.x] = ~0ull;
}

__global__ __launch_bounds__(256) void gather_zq(
    const float* __restrict__ z, const float* __restrict__ e,
    const u64* __restrict__ best, float* __restrict__ zq,
    float* __restrict__ rowp) {
  const int row = blockIdx.x;
  const u32 idx = (u32)(best[row] & 0xffffffffu);
  const float4 zv = ((const float4*)(z + (size_t)row * C_DIM))[threadIdx.x];
  const float4 ev = ((const float4*)(e + (size_t)idx * C_DIM))[threadIdx.x];
  float4 d, o;
  d.x = ev.x - zv.x; d.y = ev.y - zv.y; d.z = ev.z - zv.z; d.w = ev.w - zv.w;
  // straight-through, replicated op-for-op: z + (z_q - z)
  o.x = zv.x + d.x; o.y = zv.y + d.y; o.z = zv.z + d.z; o.w = zv.w + d.w;
  ((float4*)(zq + (size_t)row * C_DIM))[threadIdx.x] = o;
  float ss = d.x * d.x + d.y * d.y + d.z * d.z + d.w * d.w;
  ss = block_reduce_sum_256(ss);
  if (threadIdx.x == 0) rowp[row] = ss;
}

__global__ __launch_bounds__(256) void embloss_fin(const float* __restrict__ rowp,
                                                   float* __restrict__ out) {
  float s = 0.f;
  for (int i = threadIdx.x; i < B_ROWS; i += 256) s += rowp[i];
  s = block_reduce_sum_256(s);
  if (threadIdx.x == 0) out[0] = s * (1.0f / (8192.0f * 1024.0f));  // BETA=1
}

// ---------------- launch ----------------------------------------------------
extern "C" void kernel_launch(void* const* d_in, const int* in_sizes, int n_in,
                              void* d_out, int out_size, void* d_ws,
                              size_t ws_size, hipStream_t stream) {
  const float* x = (const float*)d_in[0];
  const float* enc_W = (const float*)d_in[1];
  const float* enc_b = (const float*)d_in[2];
  const float* enc_g = (const float*)d_in[3];
  const float* enc_be = (const float*)d_in[4];
  const float* enc_vW1 = (const float*)d_in[5];
  const float* enc_vb1 = (const float*)d_in[6];
  const float* enc_vW2 = (const float*)d_in[7];
  const float* enc_vb2 = (const float*)d_in[8];
  const float* dec_W = (const float*)d_in[9];
  const float* dec_b = (const float*)d_in[10];
  const float* dec_g = (const float*)d_in[11];
  const float* dec_be = (const float*)d_in[12];
  const float* dec_vW1 = (const float*)d_in[13];
  const float* dec_vb1 = (const float*)d_in[14];
  const float* dec_vW2 = (const float*)d_in[15];
  const float* dec_vb2 = (const float*)d_in[16];
  const float* cb = (const float*)d_in[17];

  // workspace layout (~128.3 MiB of fp32)
  float* ws = (float*)d_ws;
  float* e = ws;                                  // 8192*1024
  float* b0 = e + (size_t)N_EMB * C_DIM;          // 8192*1024
  float* b1 = b0 + (size_t)B_ROWS * C_DIM;        // 8192*1024
  float* b2 = b1 + (size_t)B_ROWS * C_DIM;        // 8192*1024
  float* se = b2 + (size_t)B_ROWS * C_DIM;        // 8192
  float* zz = se + N_EMB;                         // 8192
  u64* best = (u64*)(zz + B_ROWS);                // 8192 u64
  float* p1 = (float*)(best + B_ROWS);            // 16*1024
  float* p2 = p1 + 16 * C_DIM;                    // 16*1024
  float* mean = p2 + 16 * C_DIM;                  // 1024
  float* scal = mean + C_DIM;                     // 1024
  float* rowp = scal + C_DIM;                     // 8192

  float* xrec = (float*)d_out;
  float* loss = xrec + (size_t)B_ROWS * C_DIM;

  const dim3 blk(256);
  const dim3 gemmGrid(C_DIM / 128, B_ROWS / 128);  // (8, 64)
  const dim3 distGrid(N_EMB / 128, B_ROWS / 128);  // (64, 64)

  // codebook renormalize (reference normalizes again) + |e_k|^2
  l2norm_rows<<<N_EMB, blk, 0, stream>>>(cb, e, se);

  // ---- encoder MLP blocks ----
  const float* cur = x;
  for (int i = 0; i < 4; ++i) {
    gemm_nt<0><<<gemmGrid, blk, 0, stream>>>(
        cur, enc_W + (size_t)i * C_DIM * C_DIM, enc_b + i * C_DIM, b0, nullptr,
        nullptr, B_ROWS, C_DIM, C_DIM);
    bn_stats1<<<dim3(C_DIM / 64, B_ROWS / 512), blk, 0, stream>>>(b0, p1, p2);
    bn_stats2<<<dim3(C_DIM / 256), blk, 0, stream>>>(p1, p2, enc_g + i * C_DIM,
                                                     mean, scal);
    bn_relu_apply<<<dim3(B_ROWS * C_DIM / 1024), blk, 0, stream>>>(
        b0, mean, scal, enc_be + i * C_DIM, b1);
    cur = b1;
  }
  // ---- encoder VQ head: tanh(h@W1^T+b1)@W2^T+b2 ----
  gemm_nt<1><<<gemmGrid, blk, 0, stream>>>(b1, enc_vW1, enc_vb1, b0, nullptr,
                                           nullptr, B_ROWS, C_DIM, C_DIM);
  gemm_nt<0><<<gemmGrid, blk, 0, stream>>>(b0, enc_vW2, enc_vb2, b2, nullptr,
                                           nullptr, B_ROWS, C_DIM, C_DIM);

  // ---- quantizer ----
  l2norm_rows<<<B_ROWS, blk, 0, stream>>>(b2, b2, zz);  // z in-place + |z|^2
  init_best<<<B_ROWS / 256, blk, 0, stream>>>(best);
  gemm_nt<2><<<distGrid, blk, 0, stream>>>(b2, e, se, nullptr, zz, best,
                                           B_ROWS, N_EMB, C_DIM);
  gather_zq<<<B_ROWS, blk, 0, stream>>>(b2, e, best, b1, rowp);
  embloss_fin<<<1, blk, 0, stream>>>(rowp, loss);

  // ---- decoder MLP blocks ----
  cur = b1;
  for (int i = 0; i < 4; ++i) {
    gemm_nt<0><<<gemmGrid, blk, 0, stream>>>(
        cur, dec_W + (size_t)i * C_DIM * C_DIM, dec_b + i * C_DIM, b0, nullptr,
        nullptr, B_ROWS, C_DIM, C_DIM);
    bn_stats1<<<dim3(C_DIM / 64, B_ROWS / 512), blk, 0, stream>>>(b0, p1, p2);
    bn_stats2<<<dim3(C_DIM / 256), blk, 0, stream>>>(p1, p2, dec_g + i * C_DIM,
                                                     mean, scal);
    bn_relu_apply<<<dim3(B_ROWS * C_DIM / 1024), blk, 0, stream>>>(
        b0, mean, scal, dec_be + i * C_DIM, b1);
    cur = b1;
  }
  // ---- decoder VQ head -> xrec ----
  gemm_nt<1><<<gemmGrid, blk, 0, stream>>>(b1, dec_vW1, dec_vb1, b0, nullptr,
                                           nullptr, B_ROWS, C_DIM, C_DIM);
  gemm_nt<0><<<gemmGrid, blk, 0, stream>>>(b0, dec_vW2, dec_vb2, xrec, nullptr,
                                           nullptr, B_ROWS, C_DIM, C_DIM);
}

// Round 2
// 2512.552 us; speedup vs baseline: 1.8451x; 1.8451x over previous
//
#include <hip/hip_runtime.h>

typedef unsigned int u32;
typedef unsigned short u16;
typedef unsigned long long u64;

typedef __attribute__((ext_vector_type(8))) short short8;     // MFMA A/B frag (8 bf16)
typedef __attribute__((ext_vector_type(4))) float f32x4;      // MFMA C/D frag
typedef __attribute__((ext_vector_type(8))) unsigned short u16x8;
typedef __attribute__((ext_vector_type(4))) unsigned short u16x4;

#define C_DIM 1024
#define B_ROWS 8192
#define N_EMB 8192
#define BN_EPS_C 1e-5f

// ---------------- bf16 split helpers ---------------------------------------
__device__ __forceinline__ u16 f2bf_rne(float x) {
  u32 b = __float_as_uint(x);
  u32 r = b + 0x7fffu + ((b >> 16) & 1u);
  return (u16)(r >> 16);
}
__device__ __forceinline__ float bf2f(u16 h) {
  return __uint_as_float(((u32)h) << 16);
}

// ---------------- deterministic block reduce (256 threads) ----------------
__device__ __forceinline__ float block_reduce_sum_256(float v) {
#pragma unroll
  for (int off = 32; off > 0; off >>= 1) v += __shfl_xor(v, off, 64);
  __shared__ float sh[4];
  __syncthreads();
  const int lane = threadIdx.x & 63, w = threadIdx.x >> 6;
  if (lane == 0) sh[w] = v;
  __syncthreads();
  return (sh[0] + sh[1]) + (sh[2] + sh[3]);
}

__device__ __forceinline__ u64 shfl_xor_u64_16(u64 v, int m) {
  int lo = __shfl_xor((int)(u32)v, m, 16);
  int hi = __shfl_xor((int)(u32)(v >> 32), m, 16);
  return ((u64)(u32)hi << 32) | (u32)lo;
}
__device__ __forceinline__ u64 shfl_xor_u64(u64 v, int m) {
  int lo = __shfl_xor((int)(u32)v, m, 64);
  int hi = __shfl_xor((int)(u32)(v >> 32), m, 64);
  return ((u64)(u32)hi << 32) | (u32)lo;
}

// ---------------- row L2 normalize, optional fp32 + hi/lo outputs ----------
// Math identical to round-1 l2norm_rows (keeps z / zz / se bitwise).
template <int WF32>
__global__ __launch_bounds__(256) void l2norm_ext(const float* __restrict__ in,
                                                  float* __restrict__ outF,
                                                  u16* __restrict__ outH,
                                                  u16* __restrict__ outL,
                                                  float* __restrict__ ssq) {
  const int row = blockIdx.x;
  const float4 v = ((const float4*)(in + (size_t)row * C_DIM))[threadIdx.x];
  float ss = v.x * v.x + v.y * v.y + v.z * v.z + v.w * v.w;
  ss = block_reduce_sum_256(ss);
  float nrm = sqrtf(ss);
  nrm = fmaxf(nrm, 1e-12f);
  float4 o;
  o.x = v.x / nrm; o.y = v.y / nrm; o.z = v.z / nrm; o.w = v.w / nrm;
  if (WF32) ((float4*)(outF + (size_t)row * C_DIM))[threadIdx.x] = o;
  u16x4 h, l;
  h.x = f2bf_rne(o.x); l.x = f2bf_rne(o.x - bf2f(h.x));
  h.y = f2bf_rne(o.y); l.y = f2bf_rne(o.y - bf2f(h.y));
  h.z = f2bf_rne(o.z); l.z = f2bf_rne(o.z - bf2f(h.z));
  h.w = f2bf_rne(o.w); l.w = f2bf_rne(o.w - bf2f(h.w));
  ((u16x4*)(outH + (size_t)row * C_DIM))[threadIdx.x] = h;
  ((u16x4*)(outL + (size_t)row * C_DIM))[threadIdx.x] = l;
  float s2 = o.x * o.x + o.y * o.y + o.z * o.z + o.w * o.w;
  s2 = block_reduce_sum_256(s2);
  if (threadIdx.x == 0) ssq[row] = s2;
}

// ---------------- fp32 NT GEMM (round-1, bitwise-frozen encoder path) ------
template <int MODE>
__global__ __launch_bounds__(256) void gemm_nt(
    const float* __restrict__ A, const float* __restrict__ W,
    const float* __restrict__ bias, float* __restrict__ out,
    const float* __restrict__ zz, u64* __restrict__ best, int M, int N, int K) {
  __shared__ float As[16][128];
  __shared__ float Bs[16][128];
  const int tid = threadIdx.x;
  const int tx = tid & 15, ty = tid >> 4;
  const int m0 = blockIdx.y * 128, n0 = blockIdx.x * 128;
  const int lrow = tid >> 2;
  const int lkq = (tid & 3) << 2;

  const float* aPtr = A + (size_t)(m0 + lrow) * K + lkq;
  const float* bPtr = W + (size_t)(n0 + lrow) * K + lkq;
  const size_t rowStride = (size_t)64 * K;

  float acc[2][2][4][4];
#pragma unroll
  for (int p = 0; p < 2; ++p)
#pragma unroll
    for (int q = 0; q < 2; ++q)
#pragma unroll
      for (int i = 0; i < 4; ++i)
#pragma unroll
        for (int j = 0; j < 4; ++j) acc[p][q][i][j] = 0.f;

  for (int k0 = 0; k0 < K; k0 += 16) {
    const float4 a0 = *(const float4*)(aPtr + k0);
    const float4 a1 = *(const float4*)(aPtr + rowStride + k0);
    const float4 b0 = *(const float4*)(bPtr + k0);
    const float4 b1 = *(const float4*)(bPtr + rowStride + k0);
    __syncthreads();
    As[lkq + 0][lrow] = a0.x; As[lkq + 1][lrow] = a0.y;
    As[lkq + 2][lrow] = a0.z; As[lkq + 3][lrow] = a0.w;
    As[lkq + 0][lrow + 64] = a1.x; As[lkq + 1][lrow + 64] = a1.y;
    As[lkq + 2][lrow + 64] = a1.z; As[lkq + 3][lrow + 64] = a1.w;
    Bs[lkq + 0][lrow] = b0.x; Bs[lkq + 1][lrow] = b0.y;
    Bs[lkq + 2][lrow] = b0.z; Bs[lkq + 3][lrow] = b0.w;
    Bs[lkq + 0][lrow + 64] = b1.x; Bs[lkq + 1][lrow + 64] = b1.y;
    Bs[lkq + 2][lrow + 64] = b1.z; Bs[lkq + 3][lrow + 64] = b1.w;
    __syncthreads();

    float accl[2][2][4][4];
#pragma unroll
    for (int p = 0; p < 2; ++p)
#pragma unroll
      for (int q = 0; q < 2; ++q)
#pragma unroll
        for (int i = 0; i < 4; ++i)
#pragma unroll
          for (int j = 0; j < 4; ++j) accl[p][q][i][j] = 0.f;

#pragma unroll
    for (int k = 0; k < 16; ++k) {
      float ar[2][4], br[2][4];
      *(float4*)&ar[0][0] = *(const float4*)&As[k][ty * 4];
      *(float4*)&ar[1][0] = *(const float4*)&As[k][ty * 4 + 64];
      *(float4*)&br[0][0] = *(const float4*)&Bs[k][tx * 4];
      *(float4*)&br[1][0] = *(const float4*)&Bs[k][tx * 4 + 64];
#pragma unroll
      for (int p = 0; p < 2; ++p)
#pragma unroll
        for (int q = 0; q < 2; ++q)
#pragma unroll
          for (int i = 0; i < 4; ++i)
#pragma unroll
            for (int j = 0; j < 4; ++j) accl[p][q][i][j] += ar[p][i] * br[q][j];
    }
#pragma unroll
    for (int p = 0; p < 2; ++p)
#pragma unroll
      for (int q = 0; q < 2; ++q)
#pragma unroll
        for (int i = 0; i < 4; ++i)
#pragma unroll
          for (int j = 0; j < 4; ++j) acc[p][q][i][j] += accl[p][q][i][j];
  }

  if (MODE == 2) {
    float s4[2][4];
    *(float4*)&s4[0][0] = *(const float4*)(bias + n0 + tx * 4);
    *(float4*)&s4[1][0] = *(const float4*)(bias + n0 + 64 + tx * 4);
#pragma unroll
    for (int p = 0; p < 2; ++p)
#pragma unroll
      for (int i = 0; i < 4; ++i) {
        const int row = m0 + p * 64 + ty * 4 + i;
        const float zr = zz[row];
        u64 bkey = ~0ull;
#pragma unroll
        for (int q = 0; q < 2; ++q)
#pragma unroll
          for (int j = 0; j < 4; ++j) {
            const float d = (zr + s4[q][j]) - 2.0f * acc[p][q][i][j];
            const u32 fb = __float_as_uint(d);
            const u32 k32 = (fb & 0x80000000u) ? ~fb : (fb | 0x80000000u);
            const u64 key = ((u64)k32 << 32) | (u32)(n0 + q * 64 + tx * 4 + j);
            bkey = (key < bkey) ? key : bkey;
          }
#pragma unroll
        for (int mm = 1; mm < 16; mm <<= 1) {
          const u64 o = shfl_xor_u64_16(bkey, mm);
          bkey = (o < bkey) ? o : bkey;
        }
        if (tx == 0) atomicMin(best + row, bkey);
      }
  } else {
    float bb[2][4];
    *(float4*)&bb[0][0] = *(const float4*)(bias + n0 + tx * 4);
    *(float4*)&bb[1][0] = *(const float4*)(bias + n0 + 64 + tx * 4);
#pragma unroll
    for (int p = 0; p < 2; ++p)
#pragma unroll
      for (int i = 0; i < 4; ++i) {
        const int row = m0 + p * 64 + ty * 4 + i;
#pragma unroll
        for (int q = 0; q < 2; ++q) {
          float4 r;
          r.x = acc[p][q][i][0] + bb[q][0];
          r.y = acc[p][q][i][1] + bb[q][1];
          r.z = acc[p][q][i][2] + bb[q][2];
          r.w = acc[p][q][i][3] + bb[q][3];
          if (MODE == 1) {
            r.x = tanhf(r.x); r.y = tanhf(r.y);
            r.z = tanhf(r.z); r.w = tanhf(r.w);
          }
          *(float4*)(out + (size_t)row * N + n0 + q * 64 + tx * 4) = r;
        }
      }
  }
}

// ---------------- split-bf16 3-term MFMA NT GEMM ---------------------------
// C = A@W^T where A ~ Ah+Al, W ~ Bh+Bl (bf16 hi/lo).  acc = hh + hl + lh.
// MODE 0: +bias -> fp32 out.  MODE 1: +bias, tanh -> hi/lo out.
// MODE 2: distance argmin (bias = |e|^2, uses zz/best).
template <int MODE>
__global__ __launch_bounds__(256, 2) void gemm_bf3(
    const u16* __restrict__ Ahg, const u16* __restrict__ Alg,
    const u16* __restrict__ Bhg, const u16* __restrict__ Blg,
    const float* __restrict__ bias, float* __restrict__ outF,
    u16* __restrict__ outH, u16* __restrict__ outL,
    const float* __restrict__ zz, u64* __restrict__ best, int N, int K) {
  __shared__ __align__(16) u16 Ah[128 * 32];
  __shared__ __align__(16) u16 Al[128 * 32];
  __shared__ __align__(16) u16 Bh[128 * 32];
  __shared__ __align__(16) u16 Bl[128 * 32];
  const int tid = threadIdx.x;
  const int lane = tid & 63, w = tid >> 6;
  const int wr = w >> 1, wc = w & 1;
  const int m0 = blockIdx.y * 128, n0 = blockIdx.x * 128;
  const int r0 = tid >> 2, q0 = tid & 3;

  f32x4 acc[4][4];
#pragma unroll
  for (int i = 0; i < 4; ++i)
#pragma unroll
    for (int j = 0; j < 4; ++j) acc[i][j] = (f32x4){0.f, 0.f, 0.f, 0.f};

  for (int k0 = 0; k0 < K; k0 += 32) {
    u16x8 va[2], vla[2], vb[2], vlb[2];
#pragma unroll
    for (int p = 0; p < 2; ++p) {
      const int r = p * 64 + r0;
      const size_t ga = (size_t)(m0 + r) * K + k0 + q0 * 8;
      const size_t gb = (size_t)(n0 + r) * K + k0 + q0 * 8;
      va[p] = *(const u16x8*)(Ahg + ga);
      vla[p] = *(const u16x8*)(Alg + ga);
      vb[p] = *(const u16x8*)(Bhg + gb);
      vlb[p] = *(const u16x8*)(Blg + gb);
    }
    __syncthreads();
#pragma unroll
    for (int p = 0; p < 2; ++p) {
      const int r = p * 64 + r0;
      const int off = r * 32 + (q0 ^ ((r >> 1) & 3)) * 8;
      *(u16x8*)(Ah + off) = va[p];
      *(u16x8*)(Al + off) = vla[p];
      *(u16x8*)(Bh + off) = vb[p];
      *(u16x8*)(Bl + off) = vlb[p];
    }
    __syncthreads();

    short8 ah[4], al[4], bh[4], bl[4];
    const int q = lane >> 4;
#pragma unroll
    for (int t = 0; t < 4; ++t) {
      const int ra = wr * 64 + t * 16 + (lane & 15);
      const int oa = ra * 32 + (q ^ ((ra >> 1) & 3)) * 8;
      ah[t] = *(const short8*)(Ah + oa);
      al[t] = *(const short8*)(Al + oa);
      const int rb = wc * 64 + t * 16 + (lane & 15);
      const int ob = rb * 32 + (q ^ ((rb >> 1) & 3)) * 8;
      bh[t] = *(const short8*)(Bh + ob);
      bl[t] = *(const short8*)(Bl + ob);
    }
#pragma unroll
    for (int i = 0; i < 4; ++i)
#pragma unroll
      for (int j = 0; j < 4; ++j) {
        acc[i][j] = __builtin_amdgcn_mfma_f32_16x16x32_bf16(ah[i], bh[j],
                                                            acc[i][j], 0, 0, 0);
        acc[i][j] = __builtin_amdgcn_mfma_f32_16x16x32_bf16(ah[i], bl[j],
                                                            acc[i][j], 0, 0, 0);
        acc[i][j] = __builtin_amdgcn_mfma_f32_16x16x32_bf16(al[i], bh[j],
                                                            acc[i][j], 0, 0, 0);
      }
  }

  // C/D layout: col = lane&15, row = (lane>>4)*4 + v   [m89-verified]
  const int rbase = m0 + wr * 64 + (lane >> 4) * 4;
  const int cbase = n0 + wc * 64 + (lane & 15);

  if (MODE == 2) {
    float sev[4];
#pragma unroll
    for (int j = 0; j < 4; ++j) sev[j] = bias[cbase + j * 16];
#pragma unroll
    for (int i = 0; i < 4; ++i)
#pragma unroll
      for (int v = 0; v < 4; ++v) {
        const int row = rbase + i * 16 + v;
        const float zr = zz[row];
        u64 bkey = ~0ull;
#pragma unroll
        for (int j = 0; j < 4; ++j) {
          const float d = (zr + sev[j]) - 2.0f * acc[i][j][v];
          const u32 fb = __float_as_uint(d);
          const u32 k32 = (fb & 0x80000000u) ? ~fb : (fb | 0x80000000u);
          const u64 key = ((u64)k32 << 32) | (u32)(cbase + j * 16);
          bkey = (key < bkey) ? key : bkey;
        }
#pragma unroll
        for (int mm = 1; mm < 16; mm <<= 1) {
          const u64 o = shfl_xor_u64(bkey, mm);
          bkey = (o < bkey) ? o : bkey;
        }
        if ((lane & 15) == 0) atomicMin(best + row, bkey);
      }
  } else {
    float bb[4];
#pragma unroll
    for (int j = 0; j < 4; ++j) bb[j] = bias[cbase + j * 16];
#pragma unroll
    for (int i = 0; i < 4; ++i)
#pragma unroll
      for (int j = 0; j < 4; ++j)
#pragma unroll
        for (int v = 0; v < 4; ++v) {
          const int row = rbase + i * 16 + v;
          const int col = cbase + j * 16;
          float val = acc[i][j][v] + bb[j];
          if (MODE == 1) {
            val = tanhf(val);
            const u16 h = f2bf_rne(val);
            outH[(size_t)row * N + col] = h;
            outL[(size_t)row * N + col] = f2bf_rne(val - bf2f(h));
          } else {
            outF[(size_t)row * N + col] = val;
          }
        }
  }
}

// ---------------- fp32 -> bf16 hi/lo conversion ----------------------------
__global__ __launch_bounds__(256) void cvt_split(const float* __restrict__ in,
                                                 u16* __restrict__ hi,
                                                 u16* __restrict__ lo, int n4) {
  const int i = blockIdx.x * 256 + threadIdx.x;
  if (i >= n4) return;
  const float4 v = ((const float4*)in)[i];
  u16x4 h, l;
  h.x = f2bf_rne(v.x); l.x = f2bf_rne(v.x - bf2f(h.x));
  h.y = f2bf_rne(v.y); l.y = f2bf_rne(v.y - bf2f(h.y));
  h.z = f2bf_rne(v.z); l.z = f2bf_rne(v.z - bf2f(h.z));
  h.w = f2bf_rne(v.w); l.w = f2bf_rne(v.w - bf2f(h.w));
  ((u16x4*)hi)[i] = h;
  ((u16x4*)lo)[i] = l;
}

// ---------------- BatchNorm batch-stats (deterministic two-stage) -----------
__global__ __launch_bounds__(256) void bn_stats1(const float* __restrict__ t,
                                                 float* __restrict__ p1,
                                                 float* __restrict__ p2) {
  const int tx = threadIdx.x & 63, ty = threadIdx.x >> 6;
  const int c = blockIdx.x * 64 + tx;
  const int r0 = blockIdx.y * 512;
  float s = 0.f, ss = 0.f;
  for (int i = ty; i < 512; i += 4) {
    const float v = t[(size_t)(r0 + i) * C_DIM + c];
    s += v;
    ss += v * v;
  }
  __shared__ float sh1[4][64], sh2[4][64];
  sh1[ty][tx] = s;
  sh2[ty][tx] = ss;
  __syncthreads();
  if (ty == 0) {
    s = (sh1[0][tx] + sh1[1][tx]) + (sh1[2][tx] + sh1[3][tx]);
    ss = (sh2[0][tx] + sh2[1][tx]) + (sh2[2][tx] + sh2[3][tx]);
    p1[blockIdx.y * C_DIM + c] = s;
    p2[blockIdx.y * C_DIM + c] = ss;
  }
}

__global__ __launch_bounds__(256) void bn_stats2(const float* __restrict__ p1,
                                                 const float* __restrict__ p2,
                                                 const float* __restrict__ g,
                                                 float* __restrict__ mean,
                                                 float* __restrict__ scale) {
  const int c = blockIdx.x * 256 + threadIdx.x;
  float s = 0.f, ss = 0.f;
  for (int i = 0; i < 16; ++i) {
    s += p1[i * C_DIM + c];
    ss += p2[i * C_DIM + c];
  }
  const float m = s * (1.0f / 8192.0f);
  const float v = ss * (1.0f / 8192.0f) - m * m;
  mean[c] = m;
  scale[c] = g[c] / sqrtf(v + BN_EPS_C);
}

__global__ __launch_bounds__(256) void bn_relu_apply(
    const float* __restrict__ t, const float* __restrict__ mean,
    const float* __restrict__ scale, const float* __restrict__ be,
    float* __restrict__ out) {
  const int i = blockIdx.x * 256 + threadIdx.x;
  const int c4 = i & 255;
  const float4 v = ((const float4*)t)[i];
  const float4 m = ((const float4*)mean)[c4];
  const float4 sc = ((const float4*)scale)[c4];
  const float4 b = ((const float4*)be)[c4];
  float4 r;
  r.x = fmaxf((v.x - m.x) * sc.x + b.x, 0.f);
  r.y = fmaxf((v.y - m.y) * sc.y + b.y, 0.f);
  r.z = fmaxf((v.z - m.z) * sc.z + b.z, 0.f);
  r.w = fmaxf((v.w - m.w) * sc.w + b.w, 0.f);
  ((float4*)out)[i] = r;
}

__global__ __launch_bounds__(256) void bn_relu_cvt(
    const float* __restrict__ t, const float* __restrict__ mean,
    const float* __restrict__ scale, const float* __restrict__ be,
    u16* __restrict__ outH, u16* __restrict__ outL) {
  const int i = blockIdx.x * 256 + threadIdx.x;
  const int c4 = i & 255;
  const float4 v = ((const float4*)t)[i];
  const float4 m = ((const float4*)mean)[c4];
  const float4 sc = ((const float4*)scale)[c4];
  const float4 b = ((const float4*)be)[c4];
  float4 r;
  r.x = fmaxf((v.x - m.x) * sc.x + b.x, 0.f);
  r.y = fmaxf((v.y - m.y) * sc.y + b.y, 0.f);
  r.z = fmaxf((v.z - m.z) * sc.z + b.z, 0.f);
  r.w = fmaxf((v.w - m.w) * sc.w + b.w, 0.f);
  u16x4 h, l;
  h.x = f2bf_rne(r.x); l.x = f2bf_rne(r.x - bf2f(h.x));
  h.y = f2bf_rne(r.y); l.y = f2bf_rne(r.y - bf2f(h.y));
  h.z = f2bf_rne(r.z); l.z = f2bf_rne(r.z - bf2f(h.z));
  h.w = f2bf_rne(r.w); l.w = f2bf_rne(r.w - bf2f(h.w));
  ((u16x4*)outH)[i] = h;
  ((u16x4*)outL)[i] = l;
}

// ---------------- VQ pieces -------------------------------------------------
__global__ __launch_bounds__(256) void init_best(u64* __restrict__ best) {
  best[blockIdx.x * 256 + threadIdx.x] = ~0ull;
}

__global__ __launch_bounds__(256) void gather_zq_cvt(
    const float* __restrict__ z, const u16* __restrict__ eh,
    const u16* __restrict__ el, const u64* __restrict__ best,
    u16* __restrict__ zqh, u16* __restrict__ zql, float* __restrict__ rowp) {
  const int row = blockIdx.x;
  const u32 idx = (u32)(best[row] & 0xffffffffu);
  const float4 zv = ((const float4*)(z + (size_t)row * C_DIM))[threadIdx.x];
  const u16x4 evh = ((const u16x4*)(eh + (size_t)idx * C_DIM))[threadIdx.x];
  const u16x4 evl = ((const u16x4*)(el + (size_t)idx * C_DIM))[threadIdx.x];
  float4 ev;
  ev.x = bf2f(evh.x) + bf2f(evl.x);
  ev.y = bf2f(evh.y) + bf2f(evl.y);
  ev.z = bf2f(evh.z) + bf2f(evl.z);
  ev.w = bf2f(evh.w) + bf2f(evl.w);
  float4 d, o;
  d.x = ev.x - zv.x; d.y = ev.y - zv.y; d.z = ev.z - zv.z; d.w = ev.w - zv.w;
  o.x = zv.x + d.x; o.y = zv.y + d.y; o.z = zv.z + d.z; o.w = zv.w + d.w;
  u16x4 h, l;
  h.x = f2bf_rne(o.x); l.x = f2bf_rne(o.x - bf2f(h.x));
  h.y = f2bf_rne(o.y); l.y = f2bf_rne(o.y - bf2f(h.y));
  h.z = f2bf_rne(o.z); l.z = f2bf_rne(o.z - bf2f(h.z));
  h.w = f2bf_rne(o.w); l.w = f2bf_rne(o.w - bf2f(h.w));
  ((u16x4*)(zqh + (size_t)row * C_DIM))[threadIdx.x] = h;
  ((u16x4*)(zql + (size_t)row * C_DIM))[threadIdx.x] = l;
  float ss = d.x * d.x + d.y * d.y + d.z * d.z + d.w * d.w;
  ss = block_reduce_sum_256(ss);
  if (threadIdx.x == 0) rowp[row] = ss;
}

__global__ __launch_bounds__(256) void embloss_fin(const float* __restrict__ rowp,
                                                   float* __restrict__ out) {
  float s = 0.f;
  for (int i = threadIdx.x; i < B_ROWS; i += 256) s += rowp[i];
  s = block_reduce_sum_256(s);
  if (threadIdx.x == 0) out[0] = s * (1.0f / (8192.0f * 1024.0f));
}

// ---------------- launch ----------------------------------------------------
extern "C" void kernel_launch(void* const* d_in, const int* in_sizes, int n_in,
                              void* d_out, int out_size, void* d_ws,
                              size_t ws_size, hipStream_t stream) {
  const float* x = (const float*)d_in[0];
  const float* enc_W = (const float*)d_in[1];
  const float* enc_b = (const float*)d_in[2];
  const float* enc_g = (const float*)d_in[3];
  const float* enc_be = (const float*)d_in[4];
  const float* enc_vW1 = (const float*)d_in[5];
  const float* enc_vb1 = (const float*)d_in[6];
  const float* enc_vW2 = (const float*)d_in[7];
  const float* enc_vb2 = (const float*)d_in[8];
  const float* dec_W = (const float*)d_in[9];
  const float* dec_b = (const float*)d_in[10];
  const float* dec_g = (const float*)d_in[11];
  const float* dec_be = (const float*)d_in[12];
  const float* dec_vW1 = (const float*)d_in[13];
  const float* dec_vb1 = (const float*)d_in[14];
  const float* dec_vW2 = (const float*)d_in[15];
  const float* dec_vb2 = (const float*)d_in[16];
  const float* cb = (const float*)d_in[17];

  const size_t NE = (size_t)B_ROWS * C_DIM;  // 8388608
  float* ws = (float*)d_ws;
  // R1..R4: four 8M-float regions with liveness-based overlays (total ~134.5MB)
  float* b0 = ws;            // enc/dec GEMM out; overlay: zhi/zlo during dist
  float* b1 = b0 + NE;       // enc acts;         overlay: zq/act hi+lo (decoder)
  float* b2 = b1 + NE;       // z fp32;           overlay: tanh hi+lo
  float* r4 = b2 + NE;       // overlay: ehi/elo; then dec-weight hi/lo ping
  float* se = r4 + NE;
  float* zz = se + N_EMB;
  u64* best = (u64*)(zz + B_ROWS);
  float* p1 = (float*)(best + B_ROWS);
  float* p2 = p1 + 16 * C_DIM;
  float* mean = p2 + 16 * C_DIM;
  float* scal = mean + C_DIM;
  float* rowp = scal + C_DIM;

  u16* ehi = (u16*)r4;
  u16* elo = ehi + NE;
  u16* zhi = (u16*)b0;
  u16* zlo = zhi + NE;
  u16* actH = (u16*)b1;
  u16* actL = actH + NE;
  u16* thh = (u16*)b2;
  u16* thl = thh + NE;
  u16* wbh = (u16*)r4;  // reused AFTER gather consumes ehi/elo
  u16* wbl = wbh + (size_t)C_DIM * C_DIM;

  float* xrec = (float*)d_out;
  float* loss = xrec + NE;

  const dim3 blk(256);
  const dim3 gemmGrid(C_DIM / 128, B_ROWS / 128);  // (8, 64)
  const dim3 distGrid(N_EMB / 128, B_ROWS / 128);  // (64, 64)
  const int W4 = C_DIM * C_DIM / 4;                // 262144

  // codebook: normalize -> ehi/elo + |e|^2 (se fp32, bitwise == round 1)
  l2norm_ext<0><<<N_EMB, blk, 0, stream>>>(cb, nullptr, ehi, elo, se);

  // ---- encoder (bitwise-frozen fp32 path) ----
  const float* cur = x;
  for (int i = 0; i < 4; ++i) {
    gemm_nt<0><<<gemmGrid, blk, 0, stream>>>(
        cur, enc_W + (size_t)i * C_DIM * C_DIM, enc_b + i * C_DIM, b0, nullptr,
        nullptr, B_ROWS, C_DIM, C_DIM);
    bn_stats1<<<dim3(C_DIM / 64, B_ROWS / 512), blk, 0, stream>>>(b0, p1, p2);
    bn_stats2<<<dim3(C_DIM / 256), blk, 0, stream>>>(p1, p2, enc_g + i * C_DIM,
                                                     mean, scal);
    bn_relu_apply<<<dim3(B_ROWS * C_DIM / 1024), blk, 0, stream>>>(
        b0, mean, scal, enc_be + i * C_DIM, b1);
    cur = b1;
  }
  gemm_nt<1><<<gemmGrid, blk, 0, stream>>>(b1, enc_vW1, enc_vb1, b0, nullptr,
                                           nullptr, B_ROWS, C_DIM, C_DIM);
  gemm_nt<0><<<gemmGrid, blk, 0, stream>>>(b0, enc_vW2, enc_vb2, b2, nullptr,
                                           nullptr, B_ROWS, C_DIM, C_DIM);

  // ---- quantizer ----
  l2norm_ext<1><<<B_ROWS, blk, 0, stream>>>(b2, b2, zhi, zlo, zz);
  init_best<<<B_ROWS / 256, blk, 0, stream>>>(best);
  gemm_bf3<2><<<distGrid, blk, 0, stream>>>(zhi, zlo, ehi, elo, se, nullptr,
                                            nullptr, nullptr, zz, best, N_EMB,
                                            C_DIM);
  gather_zq_cvt<<<B_ROWS, blk, 0, stream>>>(b2, ehi, elo, best, actH, actL,
                                            rowp);
  embloss_fin<<<1, blk, 0, stream>>>(rowp, loss);

  // ---- decoder (split-bf16 MFMA path) ----
  for (int i = 0; i < 4; ++i) {
    cvt_split<<<dim3(W4 / 256), blk, 0, stream>>>(
        dec_W + (size_t)i * C_DIM * C_DIM, wbh, wbl, W4);
    gemm_bf3<0><<<gemmGrid, blk, 0, stream>>>(actH, actL, wbh, wbl,
                                              dec_b + i * C_DIM, b0, nullptr,
                                              nullptr, nullptr, nullptr, C_DIM,
                                              C_DIM);
    bn_stats1<<<dim3(C_DIM / 64, B_ROWS / 512), blk, 0, stream>>>(b0, p1, p2);
    bn_stats2<<<dim3(C_DIM / 256), blk, 0, stream>>>(p1, p2, dec_g + i * C_DIM,
                                                     mean, scal);
    bn_relu_cvt<<<dim3(B_ROWS * C_DIM / 1024), blk, 0, stream>>>(
        b0, mean, scal, dec_be + i * C_DIM, actH, actL);
  }
  cvt_split<<<dim3(W4 / 256), blk, 0, stream>>>(dec_vW1, wbh, wbl, W4);
  gemm_bf3<1><<<gemmGrid, blk, 0, stream>>>(actH, actL, wbh, wbl, dec_vb1,
                                            nullptr, thh, thl, nullptr, nullptr,
                                            C_DIM, C_DIM);
  cvt_split<<<dim3(W4 / 256), blk, 0, stream>>>(dec_vW2, wbh, wbl, W4);
  gemm_bf3<0><<<gemmGrid, blk, 0, stream>>>(thh, thl, wbh, wbl, dec_vb2, xrec,
                                            nullptr, nullptr, nullptr, nullptr,
                                            C_DIM, C_DIM);
}

// Round 3
// 1657.685 us; speedup vs baseline: 2.7967x; 1.5157x over previous
//
#include <hip/hip_runtime.h>

typedef unsigned int u32;
typedef unsigned short u16;
typedef unsigned long long u64;

typedef __attribute__((ext_vector_type(8))) short short8;     // MFMA A/B frag (8 bf16)
typedef __attribute__((ext_vector_type(4))) float f32x4;      // MFMA C/D frag
typedef __attribute__((ext_vector_type(8))) unsigned short u16x8;
typedef __attribute__((ext_vector_type(4))) unsigned short u16x4;

#define C_DIM 1024
#define B_ROWS 8192
#define N_EMB 8192
#define BN_EPS_C 1e-5f

// ---------------- bf16 split helpers ---------------------------------------
__device__ __forceinline__ u16 f2bf_rne(float x) {
  u32 b = __float_as_uint(x);
  u32 r = b + 0x7fffu + ((b >> 16) & 1u);
  return (u16)(r >> 16);
}
__device__ __forceinline__ float bf2f(u16 h) {
  return __uint_as_float(((u32)h) << 16);
}

// ---------------- deterministic block reduce (256 threads) ----------------
__device__ __forceinline__ float block_reduce_sum_256(float v) {
#pragma unroll
  for (int off = 32; off > 0; off >>= 1) v += __shfl_xor(v, off, 64);
  __shared__ float sh[4];
  __syncthreads();
  const int lane = threadIdx.x & 63, w = threadIdx.x >> 6;
  if (lane == 0) sh[w] = v;
  __syncthreads();
  return (sh[0] + sh[1]) + (sh[2] + sh[3]);
}

__device__ __forceinline__ u64 shfl_xor_u64(u64 v, int m) {
  int lo = __shfl_xor((int)(u32)v, m, 64);
  int hi = __shfl_xor((int)(u32)(v >> 32), m, 64);
  return ((u64)(u32)hi << 32) | (u32)lo;
}

// ---------------- row L2 normalize, optional fp32 + hi/lo outputs ----------
template <int WF32>
__global__ __launch_bounds__(256) void l2norm_ext(const float* __restrict__ in,
                                                  float* __restrict__ outF,
                                                  u16* __restrict__ outH,
                                                  u16* __restrict__ outL,
                                                  float* __restrict__ ssq) {
  const int row = blockIdx.x;
  const float4 v = ((const float4*)(in + (size_t)row * C_DIM))[threadIdx.x];
  float ss = v.x * v.x + v.y * v.y + v.z * v.z + v.w * v.w;
  ss = block_reduce_sum_256(ss);
  float nrm = sqrtf(ss);
  nrm = fmaxf(nrm, 1e-12f);
  float4 o;
  o.x = v.x / nrm; o.y = v.y / nrm; o.z = v.z / nrm; o.w = v.w / nrm;
  if (WF32) ((float4*)(outF + (size_t)row * C_DIM))[threadIdx.x] = o;
  u16x4 h, l;
  h.x = f2bf_rne(o.x); l.x = f2bf_rne(o.x - bf2f(h.x));
  h.y = f2bf_rne(o.y); l.y = f2bf_rne(o.y - bf2f(h.y));
  h.z = f2bf_rne(o.z); l.z = f2bf_rne(o.z - bf2f(h.z));
  h.w = f2bf_rne(o.w); l.w = f2bf_rne(o.w - bf2f(h.w));
  ((u16x4*)(outH + (size_t)row * C_DIM))[threadIdx.x] = h;
  ((u16x4*)(outL + (size_t)row * C_DIM))[threadIdx.x] = l;
  float s2 = o.x * o.x + o.y * o.y + o.z * o.z + o.w * o.w;
  s2 = block_reduce_sum_256(s2);
  if (threadIdx.x == 0) ssq[row] = s2;
}

// ---------------- split-bf16 MFMA NT GEMM ----------------------------------
// C = A@W^T, A ~ Ah+Al, W ~ Bh+Bl (bf16 hi/lo).
// TERMS=3: hh+hl+lh (decoder/dist).  TERMS=4: +ll (encoder, near-fp32).
// MODE 0: +bias -> fp32 out.  MODE 1: +bias, tanh -> hi/lo out.
// MODE 2: distance argmin (bias = |e|^2, uses zz/best).
template <int MODE, int TERMS>
__global__ __launch_bounds__(256, 2) void gemm_bf3(
    const u16* __restrict__ Ahg, const u16* __restrict__ Alg,
    const u16* __restrict__ Bhg, const u16* __restrict__ Blg,
    const float* __restrict__ bias, float* __restrict__ outF,
    u16* __restrict__ outH, u16* __restrict__ outL,
    const float* __restrict__ zz, u64* __restrict__ best, int N, int K) {
  __shared__ __align__(16) u16 Ah[128 * 32];
  __shared__ __align__(16) u16 Al[128 * 32];
  __shared__ __align__(16) u16 Bh[128 * 32];
  __shared__ __align__(16) u16 Bl[128 * 32];
  const int tid = threadIdx.x;
  const int lane = tid & 63, w = tid >> 6;
  const int wr = w >> 1, wc = w & 1;
  const int m0 = blockIdx.y * 128, n0 = blockIdx.x * 128;
  const int r0 = tid >> 2, q0 = tid & 3;

  f32x4 acc[4][4];
#pragma unroll
  for (int i = 0; i < 4; ++i)
#pragma unroll
    for (int j = 0; j < 4; ++j) acc[i][j] = (f32x4){0.f, 0.f, 0.f, 0.f};

  for (int k0 = 0; k0 < K; k0 += 32) {
    u16x8 va[2], vla[2], vb[2], vlb[2];
#pragma unroll
    for (int p = 0; p < 2; ++p) {
      const int r = p * 64 + r0;
      const size_t ga = (size_t)(m0 + r) * K + k0 + q0 * 8;
      const size_t gb = (size_t)(n0 + r) * K + k0 + q0 * 8;
      va[p] = *(const u16x8*)(Ahg + ga);
      vla[p] = *(const u16x8*)(Alg + ga);
      vb[p] = *(const u16x8*)(Bhg + gb);
      vlb[p] = *(const u16x8*)(Blg + gb);
    }
    __syncthreads();
#pragma unroll
    for (int p = 0; p < 2; ++p) {
      const int r = p * 64 + r0;
      const int off = r * 32 + (q0 ^ ((r >> 1) & 3)) * 8;
      *(u16x8*)(Ah + off) = va[p];
      *(u16x8*)(Al + off) = vla[p];
      *(u16x8*)(Bh + off) = vb[p];
      *(u16x8*)(Bl + off) = vlb[p];
    }
    __syncthreads();

    short8 ah[4], al[4], bh[4], bl[4];
    const int q = lane >> 4;
#pragma unroll
    for (int t = 0; t < 4; ++t) {
      const int ra = wr * 64 + t * 16 + (lane & 15);
      const int oa = ra * 32 + (q ^ ((ra >> 1) & 3)) * 8;
      ah[t] = *(const short8*)(Ah + oa);
      al[t] = *(const short8*)(Al + oa);
      const int rb = wc * 64 + t * 16 + (lane & 15);
      const int ob = rb * 32 + (q ^ ((rb >> 1) & 3)) * 8;
      bh[t] = *(const short8*)(Bh + ob);
      bl[t] = *(const short8*)(Bl + ob);
    }
#pragma unroll
    for (int i = 0; i < 4; ++i)
#pragma unroll
      for (int j = 0; j < 4; ++j) {
        acc[i][j] = __builtin_amdgcn_mfma_f32_16x16x32_bf16(ah[i], bh[j],
                                                            acc[i][j], 0, 0, 0);
        acc[i][j] = __builtin_amdgcn_mfma_f32_16x16x32_bf16(ah[i], bl[j],
                                                            acc[i][j], 0, 0, 0);
        acc[i][j] = __builtin_amdgcn_mfma_f32_16x16x32_bf16(al[i], bh[j],
                                                            acc[i][j], 0, 0, 0);
        if (TERMS == 4)
          acc[i][j] = __builtin_amdgcn_mfma_f32_16x16x32_bf16(
              al[i], bl[j], acc[i][j], 0, 0, 0);
      }
  }

  // C/D layout: col = lane&15, row = (lane>>4)*4 + v   [m89-verified]
  const int rbase = m0 + wr * 64 + (lane >> 4) * 4;
  const int cbase = n0 + wc * 64 + (lane & 15);

  if (MODE == 2) {
    float sev[4];
#pragma unroll
    for (int j = 0; j < 4; ++j) sev[j] = bias[cbase + j * 16];
#pragma unroll
    for (int i = 0; i < 4; ++i)
#pragma unroll
      for (int v = 0; v < 4; ++v) {
        const int row = rbase + i * 16 + v;
        const float zr = zz[row];
        u64 bkey = ~0ull;
#pragma unroll
        for (int j = 0; j < 4; ++j) {
          const float d = (zr + sev[j]) - 2.0f * acc[i][j][v];
          const u32 fb = __float_as_uint(d);
          const u32 k32 = (fb & 0x80000000u) ? ~fb : (fb | 0x80000000u);
          const u64 key = ((u64)k32 << 32) | (u32)(cbase + j * 16);
          bkey = (key < bkey) ? key : bkey;
        }
#pragma unroll
        for (int mm = 1; mm < 16; mm <<= 1) {
          const u64 o = shfl_xor_u64(bkey, mm);
          bkey = (o < bkey) ? o : bkey;
        }
        if ((lane & 15) == 0) atomicMin(best + row, bkey);
      }
  } else {
    float bb[4];
#pragma unroll
    for (int j = 0; j < 4; ++j) bb[j] = bias[cbase + j * 16];
#pragma unroll
    for (int i = 0; i < 4; ++i)
#pragma unroll
      for (int j = 0; j < 4; ++j)
#pragma unroll
        for (int v = 0; v < 4; ++v) {
          const int row = rbase + i * 16 + v;
          const int col = cbase + j * 16;
          float val = acc[i][j][v] + bb[j];
          if (MODE == 1) {
            val = tanhf(val);
            const u16 h = f2bf_rne(val);
            outH[(size_t)row * N + col] = h;
            outL[(size_t)row * N + col] = f2bf_rne(val - bf2f(h));
          } else {
            outF[(size_t)row * N + col] = val;
          }
        }
  }
}

// ---------------- fp32 -> bf16 hi/lo conversion ----------------------------
__global__ __launch_bounds__(256) void cvt_split(const float* __restrict__ in,
                                                 u16* __restrict__ hi,
                                                 u16* __restrict__ lo, int n4) {
  const int i = blockIdx.x * 256 + threadIdx.x;
  if (i >= n4) return;
  const float4 v = ((const float4*)in)[i];
  u16x4 h, l;
  h.x = f2bf_rne(v.x); l.x = f2bf_rne(v.x - bf2f(h.x));
  h.y = f2bf_rne(v.y); l.y = f2bf_rne(v.y - bf2f(h.y));
  h.z = f2bf_rne(v.z); l.z = f2bf_rne(v.z - bf2f(h.z));
  h.w = f2bf_rne(v.w); l.w = f2bf_rne(v.w - bf2f(h.w));
  ((u16x4*)hi)[i] = h;
  ((u16x4*)lo)[i] = l;
}

// ---------------- BatchNorm batch-stats (deterministic two-stage) -----------
__global__ __launch_bounds__(256) void bn_stats1(const float* __restrict__ t,
                                                 float* __restrict__ p1,
                                                 float* __restrict__ p2) {
  const int tx = threadIdx.x & 63, ty = threadIdx.x >> 6;
  const int c = blockIdx.x * 64 + tx;
  const int r0 = blockIdx.y * 512;
  float s = 0.f, ss = 0.f;
  for (int i = ty; i < 512; i += 4) {
    const float v = t[(size_t)(r0 + i) * C_DIM + c];
    s += v;
    ss += v * v;
  }
  __shared__ float sh1[4][64], sh2[4][64];
  sh1[ty][tx] = s;
  sh2[ty][tx] = ss;
  __syncthreads();
  if (ty == 0) {
    s = (sh1[0][tx] + sh1[1][tx]) + (sh1[2][tx] + sh1[3][tx]);
    ss = (sh2[0][tx] + sh2[1][tx]) + (sh2[2][tx] + sh2[3][tx]);
    p1[blockIdx.y * C_DIM + c] = s;
    p2[blockIdx.y * C_DIM + c] = ss;
  }
}

__global__ __launch_bounds__(256) void bn_stats2(const float* __restrict__ p1,
                                                 const float* __restrict__ p2,
                                                 const float* __restrict__ g,
                                                 float* __restrict__ mean,
                                                 float* __restrict__ scale) {
  const int c = blockIdx.x * 256 + threadIdx.x;
  float s = 0.f, ss = 0.f;
  for (int i = 0; i < 16; ++i) {
    s += p1[i * C_DIM + c];
    ss += p2[i * C_DIM + c];
  }
  const float m = s * (1.0f / 8192.0f);
  const float v = ss * (1.0f / 8192.0f) - m * m;
  mean[c] = m;
  scale[c] = g[c] / sqrtf(v + BN_EPS_C);
}

__global__ __launch_bounds__(256) void bn_relu_cvt(
    const float* __restrict__ t, const float* __restrict__ mean,
    const float* __restrict__ scale, const float* __restrict__ be,
    u16* __restrict__ outH, u16* __restrict__ outL) {
  const int i = blockIdx.x * 256 + threadIdx.x;
  const int c4 = i & 255;
  const float4 v = ((const float4*)t)[i];
  const float4 m = ((const float4*)mean)[c4];
  const float4 sc = ((const float4*)scale)[c4];
  const float4 b = ((const float4*)be)[c4];
  float4 r;
  r.x = fmaxf((v.x - m.x) * sc.x + b.x, 0.f);
  r.y = fmaxf((v.y - m.y) * sc.y + b.y, 0.f);
  r.z = fmaxf((v.z - m.z) * sc.z + b.z, 0.f);
  r.w = fmaxf((v.w - m.w) * sc.w + b.w, 0.f);
  u16x4 h, l;
  h.x = f2bf_rne(r.x); l.x = f2bf_rne(r.x - bf2f(h.x));
  h.y = f2bf_rne(r.y); l.y = f2bf_rne(r.y - bf2f(h.y));
  h.z = f2bf_rne(r.z); l.z = f2bf_rne(r.z - bf2f(h.z));
  h.w = f2bf_rne(r.w); l.w = f2bf_rne(r.w - bf2f(h.w));
  ((u16x4*)outH)[i] = h;
  ((u16x4*)outL)[i] = l;
}

// ---------------- VQ pieces -------------------------------------------------
__global__ __launch_bounds__(256) void init_best(u64* __restrict__ best) {
  best[blockIdx.x * 256 + threadIdx.x] = ~0ull;
}

__global__ __launch_bounds__(256) void gather_zq_cvt(
    const float* __restrict__ z, const u16* __restrict__ eh,
    const u16* __restrict__ el, const u64* __restrict__ best,
    u16* __restrict__ zqh, u16* __restrict__ zql, float* __restrict__ rowp) {
  const int row = blockIdx.x;
  const u32 idx = (u32)(best[row] & 0xffffffffu);
  const float4 zv = ((const float4*)(z + (size_t)row * C_DIM))[threadIdx.x];
  const u16x4 evh = ((const u16x4*)(eh + (size_t)idx * C_DIM))[threadIdx.x];
  const u16x4 evl = ((const u16x4*)(el + (size_t)idx * C_DIM))[threadIdx.x];
  float4 ev;
  ev.x = bf2f(evh.x) + bf2f(evl.x);
  ev.y = bf2f(evh.y) + bf2f(evl.y);
  ev.z = bf2f(evh.z) + bf2f(evl.z);
  ev.w = bf2f(evh.w) + bf2f(evl.w);
  float4 d, o;
  d.x = ev.x - zv.x; d.y = ev.y - zv.y; d.z = ev.z - zv.z; d.w = ev.w - zv.w;
  o.x = zv.x + d.x; o.y = zv.y + d.y; o.z = zv.z + d.z; o.w = zv.w + d.w;
  u16x4 h, l;
  h.x = f2bf_rne(o.x); l.x = f2bf_rne(o.x - bf2f(h.x));
  h.y = f2bf_rne(o.y); l.y = f2bf_rne(o.y - bf2f(h.y));
  h.z = f2bf_rne(o.z); l.z = f2bf_rne(o.z - bf2f(h.z));
  h.w = f2bf_rne(o.w); l.w = f2bf_rne(o.w - bf2f(h.w));
  ((u16x4*)(zqh + (size_t)row * C_DIM))[threadIdx.x] = h;
  ((u16x4*)(zql + (size_t)row * C_DIM))[threadIdx.x] = l;
  float ss = d.x * d.x + d.y * d.y + d.z * d.z + d.w * d.w;
  ss = block_reduce_sum_256(ss);
  if (threadIdx.x == 0) rowp[row] = ss;
}

__global__ __launch_bounds__(256) void embloss_fin(const float* __restrict__ rowp,
                                                   float* __restrict__ out) {
  float s = 0.f;
  for (int i = threadIdx.x; i < B_ROWS; i += 256) s += rowp[i];
  s = block_reduce_sum_256(s);
  if (threadIdx.x == 0) out[0] = s * (1.0f / (8192.0f * 1024.0f));
}

// ---------------- launch ----------------------------------------------------
extern "C" void kernel_launch(void* const* d_in, const int* in_sizes, int n_in,
                              void* d_out, int out_size, void* d_ws,
                              size_t ws_size, hipStream_t stream) {
  const float* x = (const float*)d_in[0];
  const float* enc_W = (const float*)d_in[1];
  const float* enc_b = (const float*)d_in[2];
  const float* enc_g = (const float*)d_in[3];
  const float* enc_be = (const float*)d_in[4];
  const float* enc_vW1 = (const float*)d_in[5];
  const float* enc_vb1 = (const float*)d_in[6];
  const float* enc_vW2 = (const float*)d_in[7];
  const float* enc_vb2 = (const float*)d_in[8];
  const float* dec_W = (const float*)d_in[9];
  const float* dec_b = (const float*)d_in[10];
  const float* dec_g = (const float*)d_in[11];
  const float* dec_be = (const float*)d_in[12];
  const float* dec_vW1 = (const float*)d_in[13];
  const float* dec_vb1 = (const float*)d_in[14];
  const float* dec_vW2 = (const float*)d_in[15];
  const float* dec_vb2 = (const float*)d_in[16];
  const float* cb = (const float*)d_in[17];

  const size_t NE = (size_t)B_ROWS * C_DIM;  // 8388608
  const size_t WN = (size_t)C_DIM * C_DIM;   // 1048576
  float* ws = (float*)d_ws;
  // Four 32MB regions; everything overlays them by liveness (same footprint
  // as round 2, ~128.2 MB):
  float* R1 = ws;            // gemm fp32 out | enc thh/thl | zhi/zlo | dec out
  float* R2 = R1 + NE;       // act hi/lo (enc+dec) | enc vW2 weights
  float* R3 = R2 + NE;       // enc weights ping | z fp32 | dec thh/thl
  float* R4 = R3 + NE;       // ehi/elo -> dec weights ping
  float* se = R4 + NE;
  float* zz = se + N_EMB;
  u64* best = (u64*)(zz + B_ROWS);
  float* p1 = (float*)(best + B_ROWS);
  float* p2 = p1 + 16 * C_DIM;
  float* mean = p2 + 16 * C_DIM;
  float* scal = mean + C_DIM;
  float* rowp = scal + C_DIM;

  u16* ehi = (u16*)R4;
  u16* elo = ehi + NE;
  u16* actH = (u16*)R2;
  u16* actL = actH + NE;
  u16* weh = (u16*)R3;       // encoder weight ping (blocks + vW1)
  u16* wel = weh + WN;
  u16* w2h = (u16*)R2;       // enc vW2 weights (acts dead by then)
  u16* w2l = w2h + WN;
  u16* thhE = (u16*)R1;      // enc tanh hi/lo
  u16* thlE = thhE + NE;
  u16* zhi = (u16*)R1;       // z hi/lo (thh dead)
  u16* zlo = zhi + NE;
  u16* wdh = (u16*)R4;       // decoder weight ping (ehi/elo dead after gather)
  u16* wdl = wdh + WN;
  u16* thhD = (u16*)R3;      // dec tanh hi/lo (z fp32 dead after gather)
  u16* thlD = thhD + NE;
  float* zf = R3;            // z fp32 (enc vW2 out, in-place l2norm)

  float* xrec = (float*)d_out;
  float* loss = xrec + NE;

  const dim3 blk(256);
  const dim3 gemmGrid(C_DIM / 128, B_ROWS / 128);  // (8, 64)
  const dim3 distGrid(N_EMB / 128, B_ROWS / 128);  // (64, 64)
  const int W4 = (int)(WN / 4);                    // 262144
  const int A4 = (int)(NE / 4);                    // 2097152

  // codebook: normalize -> ehi/elo + |e|^2
  l2norm_ext<0><<<N_EMB, blk, 0, stream>>>(cb, nullptr, ehi, elo, se);

  // ---- encoder (4-term split-bf16 MFMA) ----
  cvt_split<<<dim3(A4 / 256), blk, 0, stream>>>(x, actH, actL, A4);
  for (int i = 0; i < 4; ++i) {
    cvt_split<<<dim3(W4 / 256), blk, 0, stream>>>(
        enc_W + (size_t)i * WN, weh, wel, W4);
    gemm_bf3<0, 4><<<gemmGrid, blk, 0, stream>>>(
        actH, actL, weh, wel, enc_b + i * C_DIM, R1, nullptr, nullptr, nullptr,
        nullptr, C_DIM, C_DIM);
    bn_stats1<<<dim3(C_DIM / 64, B_ROWS / 512), blk, 0, stream>>>(R1, p1, p2);
    bn_stats2<<<dim3(C_DIM / 256), blk, 0, stream>>>(p1, p2, enc_g + i * C_DIM,
                                                     mean, scal);
    bn_relu_cvt<<<dim3(B_ROWS * C_DIM / 1024), blk, 0, stream>>>(
        R1, mean, scal, enc_be + i * C_DIM, actH, actL);
  }
  // enc VQ head: tanh(h@W1^T+b1)@W2^T+b2
  cvt_split<<<dim3(W4 / 256), blk, 0, stream>>>(enc_vW1, weh, wel, W4);
  gemm_bf3<1, 4><<<gemmGrid, blk, 0, stream>>>(actH, actL, weh, wel, enc_vb1,
                                               nullptr, thhE, thlE, nullptr,
                                               nullptr, C_DIM, C_DIM);
  cvt_split<<<dim3(W4 / 256), blk, 0, stream>>>(enc_vW2, w2h, w2l, W4);
  gemm_bf3<0, 4><<<gemmGrid, blk, 0, stream>>>(thhE, thlE, w2h, w2l, enc_vb2,
                                               zf, nullptr, nullptr, nullptr,
                                               nullptr, C_DIM, C_DIM);

  // ---- quantizer ----
  l2norm_ext<1><<<B_ROWS, blk, 0, stream>>>(zf, zf, zhi, zlo, zz);
  init_best<<<B_ROWS / 256, blk, 0, stream>>>(best);
  gemm_bf3<2, 3><<<distGrid, blk, 0, stream>>>(zhi, zlo, ehi, elo, se, nullptr,
                                               nullptr, nullptr, zz, best,
                                               N_EMB, C_DIM);
  gather_zq_cvt<<<B_ROWS, blk, 0, stream>>>(zf, ehi, elo, best, actH, actL,
                                            rowp);
  embloss_fin<<<1, blk, 0, stream>>>(rowp, loss);

  // ---- decoder (3-term split-bf16 MFMA) ----
  for (int i = 0; i < 4; ++i) {
    cvt_split<<<dim3(W4 / 256), blk, 0, stream>>>(
        dec_W + (size_t)i * WN, wdh, wdl, W4);
    gemm_bf3<0, 3><<<gemmGrid, blk, 0, stream>>>(
        actH, actL, wdh, wdl, dec_b + i * C_DIM, R1, nullptr, nullptr, nullptr,
        nullptr, C_DIM, C_DIM);
    bn_stats1<<<dim3(C_DIM / 64, B_ROWS / 512), blk, 0, stream>>>(R1, p1, p2);
    bn_stats2<<<dim3(C_DIM / 256), blk, 0, stream>>>(p1, p2, dec_g + i * C_DIM,
                                                     mean, scal);
    bn_relu_cvt<<<dim3(B_ROWS * C_DIM / 1024), blk, 0, stream>>>(
        R1, mean, scal, dec_be + i * C_DIM, actH, actL);
  }
  cvt_split<<<dim3(W4 / 256), blk, 0, stream>>>(dec_vW1, wdh, wdl, W4);
  gemm_bf3<1, 3><<<gemmGrid, blk, 0, stream>>>(actH, actL, wdh, wdl, dec_vb1,
                                               nullptr, thhD, thlD, nullptr,
                                               nullptr, C_DIM, C_DIM);
  cvt_split<<<dim3(W4 / 256), blk, 0, stream>>>(dec_vW2, wdh, wdl, W4);
  gemm_bf3<0, 3><<<gemmGrid, blk, 0, stream>>>(thhD, thlD, wdh, wdl, dec_vb2,
                                               xrec, nullptr, nullptr, nullptr,
                                               nullptr, C_DIM, C_DIM);
}

// Round 4
// 1594.627 us; speedup vs baseline: 2.9073x; 1.0395x over previous
//
#include <hip/hip_runtime.h>

typedef unsigned int u32;
typedef unsigned short u16;
typedef unsigned long long u64;

typedef __attribute__((ext_vector_type(8))) short short8;     // MFMA A/B frag (8 bf16)
typedef __attribute__((ext_vector_type(4))) float f32x4;      // MFMA C/D frag
typedef __attribute__((ext_vector_type(8))) unsigned short u16x8;
typedef __attribute__((ext_vector_type(4))) unsigned short u16x4;

#define C_DIM 1024
#define B_ROWS 8192
#define N_EMB 8192
#define BN_EPS_C 1e-5f
#define KK 1024   // all GEMMs in this net have K = 1024
#define NKT 32    // K-tiles of 32

// ---------------- bf16 split helpers ---------------------------------------
__device__ __forceinline__ u16 f2bf_rne(float x) {
  u32 b = __float_as_uint(x);
  u32 r = b + 0x7fffu + ((b >> 16) & 1u);
  return (u16)(r >> 16);
}
__device__ __forceinline__ float bf2f(u16 h) {
  return __uint_as_float(((u32)h) << 16);
}

// async global->LDS, 16B per lane; LDS dest is wave-uniform base + lane*16
__device__ __forceinline__ void gl2lds(const u16* g, u16* l) {
  __builtin_amdgcn_global_load_lds(
      (const __attribute__((address_space(1))) void*)g,
      (__attribute__((address_space(3))) void*)l, 16, 0, 0);
}

// ---------------- deterministic block reduce (256 threads) ----------------
__device__ __forceinline__ float block_reduce_sum_256(float v) {
#pragma unroll
  for (int off = 32; off > 0; off >>= 1) v += __shfl_xor(v, off, 64);
  __shared__ float sh[4];
  __syncthreads();
  const int lane = threadIdx.x & 63, w = threadIdx.x >> 6;
  if (lane == 0) sh[w] = v;
  __syncthreads();
  return (sh[0] + sh[1]) + (sh[2] + sh[3]);
}

__device__ __forceinline__ u64 shfl_xor_u64(u64 v, int m) {
  int lo = __shfl_xor((int)(u32)v, m, 64);
  int hi = __shfl_xor((int)(u32)(v >> 32), m, 64);
  return ((u64)(u32)hi << 32) | (u32)lo;
}

// ---------------- row L2 normalize, optional fp32 + hi/lo outputs ----------
template <int WF32>
__global__ __launch_bounds__(256) void l2norm_ext(const float* __restrict__ in,
                                                  float* __restrict__ outF,
                                                  u16* __restrict__ outH,
                                                  u16* __restrict__ outL,
                                                  float* __restrict__ ssq) {
  const int row = blockIdx.x;
  const float4 v = ((const float4*)(in + (size_t)row * C_DIM))[threadIdx.x];
  float ss = v.x * v.x + v.y * v.y + v.z * v.z + v.w * v.w;
  ss = block_reduce_sum_256(ss);
  float nrm = sqrtf(ss);
  nrm = fmaxf(nrm, 1e-12f);
  float4 o;
  o.x = v.x / nrm; o.y = v.y / nrm; o.z = v.z / nrm; o.w = v.w / nrm;
  if (WF32) ((float4*)(outF + (size_t)row * C_DIM))[threadIdx.x] = o;
  u16x4 h, l;
  h.x = f2bf_rne(o.x); l.x = f2bf_rne(o.x - bf2f(h.x));
  h.y = f2bf_rne(o.y); l.y = f2bf_rne(o.y - bf2f(h.y));
  h.z = f2bf_rne(o.z); l.z = f2bf_rne(o.z - bf2f(h.z));
  h.w = f2bf_rne(o.w); l.w = f2bf_rne(o.w - bf2f(h.w));
  ((u16x4*)(outH + (size_t)row * C_DIM))[threadIdx.x] = h;
  ((u16x4*)(outL + (size_t)row * C_DIM))[threadIdx.x] = l;
  float s2 = o.x * o.x + o.y * o.y + o.z * o.z + o.w * o.w;
  s2 = block_reduce_sum_256(s2);
  if (threadIdx.x == 0) ssq[row] = s2;
}

// ---------------- split-bf16 MFMA NT GEMM (dbuf + gload_lds + counted vmcnt)
// C = A@W^T, A ~ Ah+Al, W ~ Bh+Bl (bf16 hi/lo).
// TERMS=3: hh+hl+lh (decoder/dist).  TERMS=4: +ll (encoder, near-fp32).
// MODE 0: +bias -> fp32 out.  MODE 1: +bias, tanh -> hi/lo out.
// MODE 2: distance argmin (bias = |e|^2, uses zz/best).
template <int MODE, int TERMS>
__global__ __launch_bounds__(256, 2) void gemm_bf3(
    const u16* __restrict__ Ahg, const u16* __restrict__ Alg,
    const u16* __restrict__ Bhg, const u16* __restrict__ Blg,
    const float* __restrict__ bias, float* __restrict__ outF,
    u16* __restrict__ outH, u16* __restrict__ outL,
    const float* __restrict__ zz, u64* __restrict__ best, int N) {
  // [2 bufs][4 arrays: Ah,Al,Bh,Bl][128 rows * 32 k] u16 = 64 KiB
  __shared__ __align__(16) u16 lds[2 * 4 * 4096];
  const int tid = threadIdx.x;
  const int lane = tid & 63, w = tid >> 6;
  const int wr = w >> 1, wc = w & 1;
  const int m0 = blockIdx.y * 128, n0 = blockIdx.x * 128;

  // staging: wave w covers local rows [w*32, w*32+32), two issues per array.
  // LDS linear (row r, chunk c) holds global k-chunk c ^ ((r>>1)&3)
  // (same involution the fragment reads use -> read path identical to r3).
  const int r0l = w * 32 + (lane >> 2);
  const int r1l = r0l + 16;
  const int c0 = (((lane & 3) ^ ((r0l >> 1) & 3)) << 3);
  const int c1 = (((lane & 3) ^ ((r1l >> 1) & 3)) << 3);
  const u16* pAh0 = Ahg + (size_t)(m0 + r0l) * KK + c0;
  const u16* pAh1 = Ahg + (size_t)(m0 + r1l) * KK + c1;
  const u16* pAl0 = Alg + (size_t)(m0 + r0l) * KK + c0;
  const u16* pAl1 = Alg + (size_t)(m0 + r1l) * KK + c1;
  const u16* pBh0 = Bhg + (size_t)(n0 + r0l) * KK + c0;
  const u16* pBh1 = Bhg + (size_t)(n0 + r1l) * KK + c1;
  const u16* pBl0 = Blg + (size_t)(n0 + r0l) * KK + c0;
  const u16* pBl1 = Blg + (size_t)(n0 + r1l) * KK + c1;

  auto STAGE = [&](int bsel, int ko) {
    u16* db = lds + bsel * 16384 + w * 1024;  // wave-uniform LDS dest
    gl2lds(pAh0 + ko, db);
    gl2lds(pAh1 + ko, db + 512);
    gl2lds(pAl0 + ko, db + 4096);
    gl2lds(pAl1 + ko, db + 4608);
    gl2lds(pBh0 + ko, db + 8192);
    gl2lds(pBh1 + ko, db + 8704);
    gl2lds(pBl0 + ko, db + 12288);
    gl2lds(pBl1 + ko, db + 12800);
  };

  // fragment-read offsets (u16 units), bank-conflict-free (0 in r3 PMC)
  int oa[4], ob[4];
  const int q = lane >> 4;
#pragma unroll
  for (int t = 0; t < 4; ++t) {
    const int ra = wr * 64 + t * 16 + (lane & 15);
    oa[t] = ra * 32 + ((q ^ ((ra >> 1) & 3)) << 3);
    const int rb = wc * 64 + t * 16 + (lane & 15);
    ob[t] = rb * 32 + ((q ^ ((rb >> 1) & 3)) << 3);
  }

  f32x4 acc[4][4];
#pragma unroll
  for (int i = 0; i < 4; ++i)
#pragma unroll
    for (int j = 0; j < 4; ++j) acc[i][j] = (f32x4){0.f, 0.f, 0.f, 0.f};

  STAGE(0, 0);
  for (int kt = 0; kt < NKT; ++kt) {
    if (kt + 1 < NKT) {
      STAGE((kt + 1) & 1, (kt + 1) * 32);
      // wait for CURRENT tile's 8 loads; next tile's 8 stay in flight
      asm volatile("s_waitcnt vmcnt(8)" ::: "memory");
    } else {
      asm volatile("s_waitcnt vmcnt(0)" ::: "memory");
    }
    __builtin_amdgcn_sched_barrier(0);
    __builtin_amdgcn_s_barrier();
    __builtin_amdgcn_sched_barrier(0);

    const u16* cb = lds + (kt & 1) * 16384;
    short8 ah[4], al[4], bh[4], bl[4];
#pragma unroll
    for (int t = 0; t < 4; ++t) {
      ah[t] = *(const short8*)(cb + oa[t]);
      al[t] = *(const short8*)(cb + 4096 + oa[t]);
      bh[t] = *(const short8*)(cb + 8192 + ob[t]);
      bl[t] = *(const short8*)(cb + 12288 + ob[t]);
    }
#pragma unroll
    for (int i = 0; i < 4; ++i)
#pragma unroll
      for (int j = 0; j < 4; ++j) {
        acc[i][j] = __builtin_amdgcn_mfma_f32_16x16x32_bf16(ah[i], bh[j],
                                                            acc[i][j], 0, 0, 0);
        acc[i][j] = __builtin_amdgcn_mfma_f32_16x16x32_bf16(ah[i], bl[j],
                                                            acc[i][j], 0, 0, 0);
        acc[i][j] = __builtin_amdgcn_mfma_f32_16x16x32_bf16(al[i], bh[j],
                                                            acc[i][j], 0, 0, 0);
        if (TERMS == 4)
          acc[i][j] = __builtin_amdgcn_mfma_f32_16x16x32_bf16(
              al[i], bl[j], acc[i][j], 0, 0, 0);
      }
    // all waves done reading this buffer before anyone re-stages it
    asm volatile("s_waitcnt lgkmcnt(0)" ::: "memory");
    __builtin_amdgcn_sched_barrier(0);
    __builtin_amdgcn_s_barrier();
    __builtin_amdgcn_sched_barrier(0);
  }

  // C/D layout: col = lane&15, row = (lane>>4)*4 + v   [m89-verified]
  const int rbase = m0 + wr * 64 + (lane >> 4) * 4;
  const int cbase = n0 + wc * 64 + (lane & 15);

  if (MODE == 2) {
    float sev[4];
#pragma unroll
    for (int j = 0; j < 4; ++j) sev[j] = bias[cbase + j * 16];
#pragma unroll
    for (int i = 0; i < 4; ++i)
#pragma unroll
      for (int v = 0; v < 4; ++v) {
        const int row = rbase + i * 16 + v;
        const float zr = zz[row];
        u64 bkey = ~0ull;
#pragma unroll
        for (int j = 0; j < 4; ++j) {
          const float d = (zr + sev[j]) - 2.0f * acc[i][j][v];
          const u32 fb = __float_as_uint(d);
          const u32 k32 = (fb & 0x80000000u) ? ~fb : (fb | 0x80000000u);
          const u64 key = ((u64)k32 << 32) | (u32)(cbase + j * 16);
          bkey = (key < bkey) ? key : bkey;
        }
#pragma unroll
        for (int mm = 1; mm < 16; mm <<= 1) {
          const u64 o = shfl_xor_u64(bkey, mm);
          bkey = (o < bkey) ? o : bkey;
        }
        if ((lane & 15) == 0) atomicMin(best + row, bkey);
      }
  } else {
    float bb[4];
#pragma unroll
    for (int j = 0; j < 4; ++j) bb[j] = bias[cbase + j * 16];
#pragma unroll
    for (int i = 0; i < 4; ++i)
#pragma unroll
      for (int j = 0; j < 4; ++j)
#pragma unroll
        for (int v = 0; v < 4; ++v) {
          const int row = rbase + i * 16 + v;
          const int col = cbase + j * 16;
          float val = acc[i][j][v] + bb[j];
          if (MODE == 1) {
            val = tanhf(val);
            const u16 h = f2bf_rne(val);
            outH[(size_t)row * N + col] = h;
            outL[(size_t)row * N + col] = f2bf_rne(val - bf2f(h));
          } else {
            outF[(size_t)row * N + col] = val;
          }
        }
  }
}

// ---------------- fp32 -> bf16 hi/lo conversion ----------------------------
__global__ __launch_bounds__(256) void cvt_split(const float* __restrict__ in,
                                                 u16* __restrict__ hi,
                                                 u16* __restrict__ lo, int n4) {
  const int i = blockIdx.x * 256 + threadIdx.x;
  if (i >= n4) return;
  const float4 v = ((const float4*)in)[i];
  u16x4 h, l;
  h.x = f2bf_rne(v.x); l.x = f2bf_rne(v.x - bf2f(h.x));
  h.y = f2bf_rne(v.y); l.y = f2bf_rne(v.y - bf2f(h.y));
  h.z = f2bf_rne(v.z); l.z = f2bf_rne(v.z - bf2f(h.z));
  h.w = f2bf_rne(v.w); l.w = f2bf_rne(v.w - bf2f(h.w));
  ((u16x4*)hi)[i] = h;
  ((u16x4*)lo)[i] = l;
}

// ---------------- BatchNorm batch-stats (deterministic two-stage) -----------
__global__ __launch_bounds__(256) void bn_stats1(const float* __restrict__ t,
                                                 float* __restrict__ p1,
                                                 float* __restrict__ p2) {
  const int tx = threadIdx.x & 63, ty = threadIdx.x >> 6;
  const int c = blockIdx.x * 64 + tx;
  const int r0 = blockIdx.y * 512;
  float s = 0.f, ss = 0.f;
  for (int i = ty; i < 512; i += 4) {
    const float v = t[(size_t)(r0 + i) * C_DIM + c];
    s += v;
    ss += v * v;
  }
  __shared__ float sh1[4][64], sh2[4][64];
  sh1[ty][tx] = s;
  sh2[ty][tx] = ss;
  __syncthreads();
  if (ty == 0) {
    s = (sh1[0][tx] + sh1[1][tx]) + (sh1[2][tx] + sh1[3][tx]);
    ss = (sh2[0][tx] + sh2[1][tx]) + (sh2[2][tx] + sh2[3][tx]);
    p1[blockIdx.y * C_DIM + c] = s;
    p2[blockIdx.y * C_DIM + c] = ss;
  }
}

__global__ __launch_bounds__(256) void bn_stats2(const float* __restrict__ p1,
                                                 const float* __restrict__ p2,
                                                 const float* __restrict__ g,
                                                 float* __restrict__ mean,
                                                 float* __restrict__ scale) {
  const int c = blockIdx.x * 256 + threadIdx.x;
  float s = 0.f, ss = 0.f;
  for (int i = 0; i < 16; ++i) {
    s += p1[i * C_DIM + c];
    ss += p2[i * C_DIM + c];
  }
  const float m = s * (1.0f / 8192.0f);
  const float v = ss * (1.0f / 8192.0f) - m * m;
  mean[c] = m;
  scale[c] = g[c] / sqrtf(v + BN_EPS_C);
}

__global__ __launch_bounds__(256) void bn_relu_cvt(
    const float* __restrict__ t, const float* __restrict__ mean,
    const float* __restrict__ scale, const float* __restrict__ be,
    u16* __restrict__ outH, u16* __restrict__ outL) {
  const int i = blockIdx.x * 256 + threadIdx.x;
  const int c4 = i & 255;
  const float4 v = ((const float4*)t)[i];
  const float4 m = ((const float4*)mean)[c4];
  const float4 sc = ((const float4*)scale)[c4];
  const float4 b = ((const float4*)be)[c4];
  float4 r;
  r.x = fmaxf((v.x - m.x) * sc.x + b.x, 0.f);
  r.y = fmaxf((v.y - m.y) * sc.y + b.y, 0.f);
  r.z = fmaxf((v.z - m.z) * sc.z + b.z, 0.f);
  r.w = fmaxf((v.w - m.w) * sc.w + b.w, 0.f);
  u16x4 h, l;
  h.x = f2bf_rne(r.x); l.x = f2bf_rne(r.x - bf2f(h.x));
  h.y = f2bf_rne(r.y); l.y = f2bf_rne(r.y - bf2f(h.y));
  h.z = f2bf_rne(r.z); l.z = f2bf_rne(r.z - bf2f(h.z));
  h.w = f2bf_rne(r.w); l.w = f2bf_rne(r.w - bf2f(h.w));
  ((u16x4*)outH)[i] = h;
  ((u16x4*)outL)[i] = l;
}

// ---------------- VQ pieces -------------------------------------------------
__global__ __launch_bounds__(256) void init_best(u64* __restrict__ best) {
  best[blockIdx.x * 256 + threadIdx.x] = ~0ull;
}

__global__ __launch_bounds__(256) void gather_zq_cvt(
    const float* __restrict__ z, const u16* __restrict__ eh,
    const u16* __restrict__ el, const u64* __restrict__ best,
    u16* __restrict__ zqh, u16* __restrict__ zql, float* __restrict__ rowp) {
  const int row = blockIdx.x;
  const u32 idx = (u32)(best[row] & 0xffffffffu);
  const float4 zv = ((const float4*)(z + (size_t)row * C_DIM))[threadIdx.x];
  const u16x4 evh = ((const u16x4*)(eh + (size_t)idx * C_DIM))[threadIdx.x];
  const u16x4 evl = ((const u16x4*)(el + (size_t)idx * C_DIM))[threadIdx.x];
  float4 ev;
  ev.x = bf2f(evh.x) + bf2f(evl.x);
  ev.y = bf2f(evh.y) + bf2f(evl.y);
  ev.z = bf2f(evh.z) + bf2f(evl.z);
  ev.w = bf2f(evh.w) + bf2f(evl.w);
  float4 d, o;
  d.x = ev.x - zv.x; d.y = ev.y - zv.y; d.z = ev.z - zv.z; d.w = ev.w - zv.w;
  o.x = zv.x + d.x; o.y = zv.y + d.y; o.z = zv.z + d.z; o.w = zv.w + d.w;
  u16x4 h, l;
  h.x = f2bf_rne(o.x); l.x = f2bf_rne(o.x - bf2f(h.x));
  h.y = f2bf_rne(o.y); l.y = f2bf_rne(o.y - bf2f(h.y));
  h.z = f2bf_rne(o.z); l.z = f2bf_rne(o.z - bf2f(h.z));
  h.w = f2bf_rne(o.w); l.w = f2bf_rne(o.w - bf2f(h.w));
  ((u16x4*)(zqh + (size_t)row * C_DIM))[threadIdx.x] = h;
  ((u16x4*)(zql + (size_t)row * C_DIM))[threadIdx.x] = l;
  float ss = d.x * d.x + d.y * d.y + d.z * d.z + d.w * d.w;
  ss = block_reduce_sum_256(ss);
  if (threadIdx.x == 0) rowp[row] = ss;
}

__global__ __launch_bounds__(256) void embloss_fin(const float* __restrict__ rowp,
                                                   float* __restrict__ out) {
  float s = 0.f;
  for (int i = threadIdx.x; i < B_ROWS; i += 256) s += rowp[i];
  s = block_reduce_sum_256(s);
  if (threadIdx.x == 0) out[0] = s * (1.0f / (8192.0f * 1024.0f));
}

// ---------------- launch ----------------------------------------------------
extern "C" void kernel_launch(void* const* d_in, const int* in_sizes, int n_in,
                              void* d_out, int out_size, void* d_ws,
                              size_t ws_size, hipStream_t stream) {
  const float* x = (const float*)d_in[0];
  const float* enc_W = (const float*)d_in[1];
  const float* enc_b = (const float*)d_in[2];
  const float* enc_g = (const float*)d_in[3];
  const float* enc_be = (const float*)d_in[4];
  const float* enc_vW1 = (const float*)d_in[5];
  const float* enc_vb1 = (const float*)d_in[6];
  const float* enc_vW2 = (const float*)d_in[7];
  const float* enc_vb2 = (const float*)d_in[8];
  const float* dec_W = (const float*)d_in[9];
  const float* dec_b = (const float*)d_in[10];
  const float* dec_g = (const float*)d_in[11];
  const float* dec_be = (const float*)d_in[12];
  const float* dec_vW1 = (const float*)d_in[13];
  const float* dec_vb1 = (const float*)d_in[14];
  const float* dec_vW2 = (const float*)d_in[15];
  const float* dec_vb2 = (const float*)d_in[16];
  const float* cb = (const float*)d_in[17];

  const size_t NE = (size_t)B_ROWS * C_DIM;  // 8388608
  const size_t WN = (size_t)C_DIM * C_DIM;   // 1048576
  float* ws = (float*)d_ws;
  // Four 32MB regions; everything overlays them by liveness (~128.2 MB):
  float* R1 = ws;            // gemm fp32 out | enc thh/thl | zhi/zlo | dec out
  float* R2 = R1 + NE;       // act hi/lo (enc+dec) | enc vW2 weights
  float* R3 = R2 + NE;       // enc weights ping | z fp32 | dec thh/thl
  float* R4 = R3 + NE;       // ehi/elo -> dec weights ping
  float* se = R4 + NE;
  float* zz = se + N_EMB;
  u64* best = (u64*)(zz + B_ROWS);
  float* p1 = (float*)(best + B_ROWS);
  float* p2 = p1 + 16 * C_DIM;
  float* mean = p2 + 16 * C_DIM;
  float* scal = mean + C_DIM;
  float* rowp = scal + C_DIM;

  u16* ehi = (u16*)R4;
  u16* elo = ehi + NE;
  u16* actH = (u16*)R2;
  u16* actL = actH + NE;
  u16* weh = (u16*)R3;       // encoder weight ping (blocks + vW1)
  u16* wel = weh + WN;
  u16* w2h = (u16*)R2;       // enc vW2 weights (acts dead by then)
  u16* w2l = w2h + WN;
  u16* thhE = (u16*)R1;      // enc tanh hi/lo
  u16* thlE = thhE + NE;
  u16* zhi = (u16*)R1;       // z hi/lo (thh dead)
  u16* zlo = zhi + NE;
  u16* wdh = (u16*)R4;       // decoder weight ping (ehi/elo dead after gather)
  u16* wdl = wdh + WN;
  u16* thhD = (u16*)R3;      // dec tanh hi/lo (z fp32 dead after gather)
  u16* thlD = thhD + NE;
  float* zf = R3;            // z fp32 (enc vW2 out, in-place l2norm)

  float* xrec = (float*)d_out;
  float* loss = xrec + NE;

  const dim3 blk(256);
  const dim3 gemmGrid(C_DIM / 128, B_ROWS / 128);  // (8, 64)
  const dim3 distGrid(N_EMB / 128, B_ROWS / 128);  // (64, 64)
  const int W4 = (int)(WN / 4);                    // 262144
  const int A4 = (int)(NE / 4);                    // 2097152

  // codebook: normalize -> ehi/elo + |e|^2
  l2norm_ext<0><<<N_EMB, blk, 0, stream>>>(cb, nullptr, ehi, elo, se);

  // ---- encoder (4-term split-bf16 MFMA) ----
  cvt_split<<<dim3(A4 / 256), blk, 0, stream>>>(x, actH, actL, A4);
  for (int i = 0; i < 4; ++i) {
    cvt_split<<<dim3(W4 / 256), blk, 0, stream>>>(
        enc_W + (size_t)i * WN, weh, wel, W4);
    gemm_bf3<0, 4><<<gemmGrid, blk, 0, stream>>>(
        actH, actL, weh, wel, enc_b + i * C_DIM, R1, nullptr, nullptr, nullptr,
        nullptr, C_DIM);
    bn_stats1<<<dim3(C_DIM / 64, B_ROWS / 512), blk, 0, stream>>>(R1, p1, p2);
    bn_stats2<<<dim3(C_DIM / 256), blk, 0, stream>>>(p1, p2, enc_g + i * C_DIM,
                                                     mean, scal);
    bn_relu_cvt<<<dim3(B_ROWS * C_DIM / 1024), blk, 0, stream>>>(
        R1, mean, scal, enc_be + i * C_DIM, actH, actL);
  }
  // enc VQ head: tanh(h@W1^T+b1)@W2^T+b2
  cvt_split<<<dim3(W4 / 256), blk, 0, stream>>>(enc_vW1, weh, wel, W4);
  gemm_bf3<1, 4><<<gemmGrid, blk, 0, stream>>>(actH, actL, weh, wel, enc_vb1,
                                               nullptr, thhE, thlE, nullptr,
                                               nullptr, C_DIM);
  cvt_split<<<dim3(W4 / 256), blk, 0, stream>>>(enc_vW2, w2h, w2l, W4);
  gemm_bf3<0, 4><<<gemmGrid, blk, 0, stream>>>(thhE, thlE, w2h, w2l, enc_vb2,
                                               zf, nullptr, nullptr, nullptr,
                                               nullptr, C_DIM);

  // ---- quantizer ----
  l2norm_ext<1><<<B_ROWS, blk, 0, stream>>>(zf, zf, zhi, zlo, zz);
  init_best<<<B_ROWS / 256, blk, 0, stream>>>(best);
  gemm_bf3<2, 3><<<distGrid, blk, 0, stream>>>(zhi, zlo, ehi, elo, se, nullptr,
                                               nullptr, nullptr, zz, best,
                                               N_EMB);
  gather_zq_cvt<<<B_ROWS, blk, 0, stream>>>(zf, ehi, elo, best, actH, actL,
                                            rowp);
  embloss_fin<<<1, blk, 0, stream>>>(rowp, loss);

  // ---- decoder (3-term split-bf16 MFMA) ----
  for (int i = 0; i < 4; ++i) {
    cvt_split<<<dim3(W4 / 256), blk, 0, stream>>>(
        dec_W + (size_t)i * WN, wdh, wdl, W4);
    gemm_bf3<0, 3><<<gemmGrid, blk, 0, stream>>>(
        actH, actL, wdh, wdl, dec_b + i * C_DIM, R1, nullptr, nullptr, nullptr,
        nullptr, C_DIM);
    bn_stats1<<<dim3(C_DIM / 64, B_ROWS / 512), blk, 0, stream>>>(R1, p1, p2);
    bn_stats2<<<dim3(C_DIM / 256), blk, 0, stream>>>(p1, p2, dec_g + i * C_DIM,
                                                     mean, scal);
    bn_relu_cvt<<<dim3(B_ROWS * C_DIM / 1024), blk, 0, stream>>>(
        R1, mean, scal, dec_be + i * C_DIM, actH, actL);
  }
  cvt_split<<<dim3(W4 / 256), blk, 0, stream>>>(dec_vW1, wdh, wdl, W4);
  gemm_bf3<1, 3><<<gemmGrid, blk, 0, stream>>>(actH, actL, wdh, wdl, dec_vb1,
                                               nullptr, thhD, thlD, nullptr,
                                               nullptr, C_DIM);
  cvt_split<<<dim3(W4 / 256), blk, 0, stream>>>(dec_vW2, wdh, wdl, W4);
  gemm_bf3<0, 3><<<gemmGrid, blk, 0, stream>>>(thhD, thlD, wdh, wdl, dec_vb2,
                                               xrec, nullptr, nullptr, nullptr,
                                               nullptr, C_DIM);
}

// Round 5
// 1528.875 us; speedup vs baseline: 3.0323x; 1.0430x over previous
//
#include <hip/hip_runtime.h>

typedef unsigned int u32;
typedef unsigned short u16;
typedef unsigned long long u64;

typedef __attribute__((ext_vector_type(8))) short short8;     // MFMA A/B frag (8 bf16)
typedef __attribute__((ext_vector_type(4))) float f32x4;      // MFMA C/D frag
typedef __attribute__((ext_vector_type(8))) unsigned short u16x8;

#define C_DIM 1024
#define B_ROWS 8192
#define N_EMB 8192
#define BN_EPS_C 1e-5f
#define KK 1024   // all GEMMs in this net have K = 1024

// ---------------- bf16 split helpers ---------------------------------------
__device__ __forceinline__ u16 f2bf_rne(float x) {
  u32 b = __float_as_uint(x);
  u32 r = b + 0x7fffu + ((b >> 16) & 1u);
  return (u16)(r >> 16);
}
__device__ __forceinline__ float bf2f(u16 h) {
  return __uint_as_float(((u32)h) << 16);
}

// ---------------- deterministic block reduce (256 threads) ----------------
__device__ __forceinline__ float block_reduce_sum_256(float v) {
#pragma unroll
  for (int off = 32; off > 0; off >>= 1) v += __shfl_xor(v, off, 64);
  __shared__ float sh[4];
  __syncthreads();
  const int lane = threadIdx.x & 63, w = threadIdx.x >> 6;
  if (lane == 0) sh[w] = v;
  __syncthreads();
  return (sh[0] + sh[1]) + (sh[2] + sh[3]);
}

__device__ __forceinline__ u64 shfl_xor_u64(u64 v, int m) {
  int lo = __shfl_xor((int)(u32)v, m, 64);
  int hi = __shfl_xor((int)(u32)(v >> 32), m, 64);
  return ((u64)(u32)hi << 32) | (u32)lo;
}

// ---------------- row L2 normalize (fp32 out) + |row|^2 (+opt best init) ---
__global__ __launch_bounds__(256) void l2norm_f(const float* __restrict__ in,
                                                float* __restrict__ outF,
                                                float* __restrict__ ssq,
                                                u64* __restrict__ binit) {
  const int row = blockIdx.x;
  const float4 v = ((const float4*)(in + (size_t)row * C_DIM))[threadIdx.x];
  float ss = v.x * v.x + v.y * v.y + v.z * v.z + v.w * v.w;
  ss = block_reduce_sum_256(ss);
  float nrm = sqrtf(ss);
  nrm = fmaxf(nrm, 1e-12f);
  float4 o;
  o.x = v.x / nrm; o.y = v.y / nrm; o.z = v.z / nrm; o.w = v.w / nrm;
  ((float4*)(outF + (size_t)row * C_DIM))[threadIdx.x] = o;
  float s2 = o.x * o.x + o.y * o.y + o.z * o.z + o.w * o.w;
  s2 = block_reduce_sum_256(s2);
  if (threadIdx.x == 0) {
    ssq[row] = s2;
    if (binit) binit[row] = ~0ull;
  }
}

// ---------------- fused split-bf16 MFMA NT GEMM -----------------------------
// C = A@B^T, A,B fp32 in global; hi/lo split happens during LDS staging
// (bitwise identical to the old cvt_split outputs).
// TERMS: 3 = hh+hl+lh, 4 = +ll (near-fp32).
// PRE:   1 = apply BatchNorm+ReLU to A during staging (pm/ps/pb by k-channel).
// MODE:  0 = +bias -> fp32 out. 1 = +bias, tanh -> fp32 out.
//        2 = distance argmin epilogue (bias = |e|^2, uses zz/best).
// CS:    1 = also emit per-block column sums of h (cs1=sum, cs2=sum sq).
template <int MODE, int TERMS, int PRE, int CS>
__global__ __launch_bounds__(256, 2) void gemm_f32sp(
    const float* __restrict__ A, const float* __restrict__ B,
    const float* __restrict__ bias, const float* __restrict__ pm,
    const float* __restrict__ ps, const float* __restrict__ pb,
    float* __restrict__ outF, float* __restrict__ cs1,
    float* __restrict__ cs2, const float* __restrict__ zz,
    u64* __restrict__ best, int N) {
  __shared__ __align__(16) u16 lds[4 * 4096];          // Ah|Al|Bh|Bl, 32 KiB
  __shared__ float csum[CS ? 4 * 64 * 2 : 1];
  const int tid = threadIdx.x;
  const int lane = tid & 63, w = tid >> 6;
  const int wr = w >> 1, wc = w & 1;
  const int m0 = blockIdx.y * 128, n0 = blockIdx.x * 128;
  const int r0 = tid >> 2, q0 = tid & 3;

  const float* aP0 = A + (size_t)(m0 + r0) * KK + q0 * 8;
  const float* aP1 = aP0 + (size_t)64 * KK;
  const float* bP0 = B + (size_t)(n0 + r0) * KK + q0 * 8;
  const float* bP1 = bP0 + (size_t)64 * KK;
  const int offA0 = r0 * 32 + ((q0 ^ ((r0 >> 1) & 3)) << 3);
  const int offA1 = offA0 + 64 * 32;  // (r0+64)>>1 & 3 == r0>>1 & 3

  // fragment-read offsets (u16 units), bank-conflict-free (verified r3 PMC=0)
  int oa[4], ob[4];
  const int q = lane >> 4;
#pragma unroll
  for (int t = 0; t < 4; ++t) {
    const int ra = wr * 64 + t * 16 + (lane & 15);
    oa[t] = ra * 32 + ((q ^ ((ra >> 1) & 3)) << 3);
    const int rb = wc * 64 + t * 16 + (lane & 15);
    ob[t] = rb * 32 + ((q ^ ((rb >> 1) & 3)) << 3);
  }

  f32x4 acc[4][4];
#pragma unroll
  for (int i = 0; i < 4; ++i)
#pragma unroll
    for (int j = 0; j < 4; ++j) acc[i][j] = (f32x4){0.f, 0.f, 0.f, 0.f};

  for (int k0 = 0; k0 < KK; k0 += 32) {
    float m8[8], s8[8], b8[8];
    if (PRE) {
      *(float4*)&m8[0] = *(const float4*)(pm + k0 + q0 * 8);
      *(float4*)&m8[4] = *(const float4*)(pm + k0 + q0 * 8 + 4);
      *(float4*)&s8[0] = *(const float4*)(ps + k0 + q0 * 8);
      *(float4*)&s8[4] = *(const float4*)(ps + k0 + q0 * 8 + 4);
      *(float4*)&b8[0] = *(const float4*)(pb + k0 + q0 * 8);
      *(float4*)&b8[4] = *(const float4*)(pb + k0 + q0 * 8 + 4);
    }
    const float4 a00 = *(const float4*)(aP0 + k0);
    const float4 a01 = *(const float4*)(aP0 + k0 + 4);
    const float4 a10 = *(const float4*)(aP1 + k0);
    const float4 a11 = *(const float4*)(aP1 + k0 + 4);
    const float4 b00 = *(const float4*)(bP0 + k0);
    const float4 b01 = *(const float4*)(bP0 + k0 + 4);
    const float4 b10 = *(const float4*)(bP1 + k0);
    const float4 b11 = *(const float4*)(bP1 + k0 + 4);

    auto CVT8 = [&](const float4& f0, const float4& f1, bool doPre, u16x8& h,
                    u16x8& l) {
      float f[8] = {f0.x, f0.y, f0.z, f0.w, f1.x, f1.y, f1.z, f1.w};
#pragma unroll
      for (int t = 0; t < 8; ++t) {
        float v = f[t];
        if (PRE)
          if (doPre) v = fmaxf((v - m8[t]) * s8[t] + b8[t], 0.f);
        const u16 hh = f2bf_rne(v);
        h[t] = (u16)hh;
        l[t] = f2bf_rne(v - bf2f(hh));
      }
    };
    u16x8 ah0, al0, ah1, al1, bh0, bl0, bh1, bl1;
    CVT8(a00, a01, true, ah0, al0);
    CVT8(a10, a11, true, ah1, al1);
    CVT8(b00, b01, false, bh0, bl0);
    CVT8(b10, b11, false, bh1, bl1);

    __syncthreads();
    *(u16x8*)(lds + offA0) = ah0;
    *(u16x8*)(lds + 4096 + offA0) = al0;
    *(u16x8*)(lds + offA1) = ah1;
    *(u16x8*)(lds + 4096 + offA1) = al1;
    *(u16x8*)(lds + 8192 + offA0) = bh0;
    *(u16x8*)(lds + 12288 + offA0) = bl0;
    *(u16x8*)(lds + 8192 + offA1) = bh1;
    *(u16x8*)(lds + 12288 + offA1) = bl1;
    __syncthreads();

    short8 ah[4], al[4], bh[4], bl[4];
#pragma unroll
    for (int t = 0; t < 4; ++t) {
      ah[t] = *(const short8*)(lds + oa[t]);
      al[t] = *(const short8*)(lds + 4096 + oa[t]);
      bh[t] = *(const short8*)(lds + 8192 + ob[t]);
      bl[t] = *(const short8*)(lds + 12288 + ob[t]);
    }
#pragma unroll
    for (int i = 0; i < 4; ++i)
#pragma unroll
      for (int j = 0; j < 4; ++j) {
        acc[i][j] = __builtin_amdgcn_mfma_f32_16x16x32_bf16(ah[i], bh[j],
                                                            acc[i][j], 0, 0, 0);
        acc[i][j] = __builtin_amdgcn_mfma_f32_16x16x32_bf16(ah[i], bl[j],
                                                            acc[i][j], 0, 0, 0);
        acc[i][j] = __builtin_amdgcn_mfma_f32_16x16x32_bf16(al[i], bh[j],
                                                            acc[i][j], 0, 0, 0);
        if (TERMS == 4)
          acc[i][j] = __builtin_amdgcn_mfma_f32_16x16x32_bf16(
              al[i], bl[j], acc[i][j], 0, 0, 0);
      }
  }

  // C/D layout: col = lane&15, row = (lane>>4)*4 + v   [m89-verified]
  const int rbase = m0 + wr * 64 + (lane >> 4) * 4;
  const int cbase = n0 + wc * 64 + (lane & 15);

  if (MODE == 2) {
    float sev[4];
#pragma unroll
    for (int j = 0; j < 4; ++j) sev[j] = bias[cbase + j * 16];
#pragma unroll
    for (int i = 0; i < 4; ++i)
#pragma unroll
      for (int v = 0; v < 4; ++v) {
        const int row = rbase + i * 16 + v;
        const float zr = zz[row];
        u64 bkey = ~0ull;
#pragma unroll
        for (int j = 0; j < 4; ++j) {
          const float d = (zr + sev[j]) - 2.0f * acc[i][j][v];
          const u32 fb = __float_as_uint(d);
          const u32 k32 = (fb & 0x80000000u) ? ~fb : (fb | 0x80000000u);
          const u64 key = ((u64)k32 << 32) | (u32)(cbase + j * 16);
          bkey = (key < bkey) ? key : bkey;
        }
#pragma unroll
        for (int mm = 1; mm < 16; mm <<= 1) {
          const u64 o = shfl_xor_u64(bkey, mm);
          bkey = (o < bkey) ? o : bkey;
        }
        if ((lane & 15) == 0) atomicMin(best + row, bkey);
      }
  } else {
    float bb[4];
#pragma unroll
    for (int j = 0; j < 4; ++j) bb[j] = bias[cbase + j * 16];
    float s[4] = {0.f, 0.f, 0.f, 0.f}, ss[4] = {0.f, 0.f, 0.f, 0.f};
#pragma unroll
    for (int i = 0; i < 4; ++i)
#pragma unroll
      for (int j = 0; j < 4; ++j)
#pragma unroll
        for (int v = 0; v < 4; ++v) {
          const int row = rbase + i * 16 + v;
          const int col = cbase + j * 16;
          float val = acc[i][j][v] + bb[j];
          if (MODE == 1) {
            outF[(size_t)row * N + col] = tanhf(val);
          } else {
            outF[(size_t)row * N + col] = val;
            if (CS) {
              s[j] += val;
              ss[j] += val * val;
            }
          }
        }
    if (CS) {
      // reduce the 4 lane>>4 groups (same col, different rows)
#pragma unroll
      for (int j = 0; j < 4; ++j) {
        s[j] += __shfl_xor(s[j], 16, 64);
        s[j] += __shfl_xor(s[j], 32, 64);
        ss[j] += __shfl_xor(ss[j], 16, 64);
        ss[j] += __shfl_xor(ss[j], 32, 64);
      }
      if (lane < 16) {
#pragma unroll
        for (int j = 0; j < 4; ++j) {
          csum[(w * 64 + j * 16 + lane) * 2 + 0] = s[j];
          csum[(w * 64 + j * 16 + lane) * 2 + 1] = ss[j];
        }
      }
      __syncthreads();
      if (tid < 128) {
        const int col = tid;
        const int wcc = col >> 6, idx = col & 63;
        const float S = csum[(wcc * 64 + idx) * 2 + 0] +
                        csum[((2 + wcc) * 64 + idx) * 2 + 0];
        const float SS = csum[(wcc * 64 + idx) * 2 + 1] +
                         csum[((2 + wcc) * 64 + idx) * 2 + 1];
        cs1[(size_t)blockIdx.y * C_DIM + n0 + col] = S;
        cs2[(size_t)blockIdx.y * C_DIM + n0 + col] = SS;
      }
    }
  }
}

// ---------------- BN finalize: fold 64 per-block partials -------------------
__global__ __launch_bounds__(256) void bn_stats2(const float* __restrict__ cs1,
                                                 const float* __restrict__ cs2,
                                                 const float* __restrict__ g,
                                                 float* __restrict__ mean,
                                                 float* __restrict__ scale) {
  const int c = blockIdx.x * 256 + threadIdx.x;
  float s = 0.f, ss = 0.f;
  for (int i = 0; i < 64; ++i) {
    s += cs1[i * C_DIM + c];
    ss += cs2[i * C_DIM + c];
  }
  const float m = s * (1.0f / 8192.0f);
  const float v = ss * (1.0f / 8192.0f) - m * m;  // biased var
  mean[c] = m;
  scale[c] = g[c] / sqrtf(v + BN_EPS_C);
}

// ---------------- VQ gather + row part of emb loss --------------------------
__global__ __launch_bounds__(256) void gather_zq(
    const float* __restrict__ z, const float* __restrict__ e,
    const u64* __restrict__ best, float* __restrict__ zq,
    float* __restrict__ rowp) {
  const int row = blockIdx.x;
  const u32 idx = (u32)(best[row] & 0xffffffffu);
  const float4 zv = ((const float4*)(z + (size_t)row * C_DIM))[threadIdx.x];
  const float4 ev = ((const float4*)(e + (size_t)idx * C_DIM))[threadIdx.x];
  float4 d, o;
  d.x = ev.x - zv.x; d.y = ev.y - zv.y; d.z = ev.z - zv.z; d.w = ev.w - zv.w;
  o.x = zv.x + d.x; o.y = zv.y + d.y; o.z = zv.z + d.z; o.w = zv.w + d.w;
  ((float4*)(zq + (size_t)row * C_DIM))[threadIdx.x] = o;
  float ss = d.x * d.x + d.y * d.y + d.z * d.z + d.w * d.w;
  ss = block_reduce_sum_256(ss);
  if (threadIdx.x == 0) rowp[row] = ss;
}

__global__ __launch_bounds__(256) void embloss_fin(const float* __restrict__ rowp,
                                                   float* __restrict__ out) {
  float s = 0.f;
  for (int i = threadIdx.x; i < B_ROWS; i += 256) s += rowp[i];
  s = block_reduce_sum_256(s);
  if (threadIdx.x == 0) out[0] = s * (1.0f / (8192.0f * 1024.0f));
}

// ---------------- launch ----------------------------------------------------
extern "C" void kernel_launch(void* const* d_in, const int* in_sizes, int n_in,
                              void* d_out, int out_size, void* d_ws,
                              size_t ws_size, hipStream_t stream) {
  const float* x = (const float*)d_in[0];
  const float* enc_W = (const float*)d_in[1];
  const float* enc_b = (const float*)d_in[2];
  const float* enc_g = (const float*)d_in[3];
  const float* enc_be = (const float*)d_in[4];
  const float* enc_vW1 = (const float*)d_in[5];
  const float* enc_vb1 = (const float*)d_in[6];
  const float* enc_vW2 = (const float*)d_in[7];
  const float* enc_vb2 = (const float*)d_in[8];
  const float* dec_W = (const float*)d_in[9];
  const float* dec_b = (const float*)d_in[10];
  const float* dec_g = (const float*)d_in[11];
  const float* dec_be = (const float*)d_in[12];
  const float* dec_vW1 = (const float*)d_in[13];
  const float* dec_vb1 = (const float*)d_in[14];
  const float* dec_vW2 = (const float*)d_in[15];
  const float* dec_vb2 = (const float*)d_in[16];
  const float* cb = (const float*)d_in[17];

  const size_t NE = (size_t)B_ROWS * C_DIM;  // 8388608
  const size_t WN = (size_t)C_DIM * C_DIM;   // 1048576
  float* ws = (float*)d_ws;
  // Four fp32 regions (~134.8 MB total incl. smalls, same proven footprint):
  float* R1 = ws;        // h ping | enc tanh | zq
  float* R2 = R1 + NE;   // h pong
  float* R3 = R2 + NE;   // z (in-place l2norm) | dec tanh path uses R1/R2
  float* R4 = R3 + NE;   // e (normalized codebook, fp32)
  float* se = R4 + NE;
  float* zz = se + N_EMB;
  u64* best = (u64*)(zz + B_ROWS);
  float* cs1 = (float*)(best + B_ROWS);  // 64*1024
  float* cs2 = cs1 + 64 * C_DIM;         // 64*1024
  float* mean = cs2 + 64 * C_DIM;
  float* scal = mean + C_DIM;
  float* rowp = scal + C_DIM;

  float* xrec = (float*)d_out;
  float* loss = xrec + NE;

  const dim3 blk(256);
  const dim3 gemmGrid(C_DIM / 128, B_ROWS / 128);  // (8, 64)
  const dim3 distGrid(N_EMB / 128, B_ROWS / 128);  // (64, 64)
  const dim3 s2Grid(C_DIM / 256);                  // (4)

  // codebook: normalize -> e fp32 + |e|^2
  l2norm_f<<<N_EMB, blk, 0, stream>>>(cb, R4, se, nullptr);

  // ---- encoder: 4 x (GEMM[+colsum, PRE-BN from prev] -> stats2) ----
  gemm_f32sp<0, 4, 0, 1><<<gemmGrid, blk, 0, stream>>>(
      x, enc_W, enc_b, nullptr, nullptr, nullptr, R1, cs1, cs2, nullptr,
      nullptr, C_DIM);
  bn_stats2<<<s2Grid, blk, 0, stream>>>(cs1, cs2, enc_g, mean, scal);
  gemm_f32sp<0, 4, 1, 1><<<gemmGrid, blk, 0, stream>>>(
      R1, enc_W + WN, enc_b + C_DIM, mean, scal, enc_be, R2, cs1, cs2, nullptr,
      nullptr, C_DIM);
  bn_stats2<<<s2Grid, blk, 0, stream>>>(cs1, cs2, enc_g + C_DIM, mean, scal);
  gemm_f32sp<0, 4, 1, 1><<<gemmGrid, blk, 0, stream>>>(
      R2, enc_W + 2 * WN, enc_b + 2 * C_DIM, mean, scal, enc_be + C_DIM, R1,
      cs1, cs2, nullptr, nullptr, C_DIM);
  bn_stats2<<<s2Grid, blk, 0, stream>>>(cs1, cs2, enc_g + 2 * C_DIM, mean,
                                        scal);
  gemm_f32sp<0, 4, 1, 1><<<gemmGrid, blk, 0, stream>>>(
      R1, enc_W + 3 * WN, enc_b + 3 * C_DIM, mean, scal, enc_be + 2 * C_DIM,
      R2, cs1, cs2, nullptr, nullptr, C_DIM);
  bn_stats2<<<s2Grid, blk, 0, stream>>>(cs1, cs2, enc_g + 3 * C_DIM, mean,
                                        scal);
  // enc VQ head: tanh(BN(h3)@W1^T+b1) @ W2^T + b2 -> z
  gemm_f32sp<1, 4, 1, 0><<<gemmGrid, blk, 0, stream>>>(
      R2, enc_vW1, enc_vb1, mean, scal, enc_be + 3 * C_DIM, R1, nullptr,
      nullptr, nullptr, nullptr, C_DIM);
  gemm_f32sp<0, 4, 0, 0><<<gemmGrid, blk, 0, stream>>>(
      R1, enc_vW2, enc_vb2, nullptr, nullptr, nullptr, R3, nullptr, nullptr,
      nullptr, nullptr, C_DIM);

  // ---- quantizer ----
  l2norm_f<<<B_ROWS, blk, 0, stream>>>(R3, R3, zz, best);  // z + |z|^2 + init
  gemm_f32sp<2, 3, 0, 0><<<distGrid, blk, 0, stream>>>(
      R3, R4, se, nullptr, nullptr, nullptr, nullptr, nullptr, nullptr, zz,
      best, N_EMB);
  gather_zq<<<B_ROWS, blk, 0, stream>>>(R3, R4, best, R2, rowp);
  embloss_fin<<<1, blk, 0, stream>>>(rowp, loss);

  // ---- decoder (3-term) ----
  gemm_f32sp<0, 3, 0, 1><<<gemmGrid, blk, 0, stream>>>(
      R2, dec_W, dec_b, nullptr, nullptr, nullptr, R1, cs1, cs2, nullptr,
      nullptr, C_DIM);
  bn_stats2<<<s2Grid, blk, 0, stream>>>(cs1, cs2, dec_g, mean, scal);
  gemm_f32sp<0, 3, 1, 1><<<gemmGrid, blk, 0, stream>>>(
      R1, dec_W + WN, dec_b + C_DIM, mean, scal, dec_be, R2, cs1, cs2, nullptr,
      nullptr, C_DIM);
  bn_stats2<<<s2Grid, blk, 0, stream>>>(cs1, cs2, dec_g + C_DIM, mean, scal);
  gemm_f32sp<0, 3, 1, 1><<<gemmGrid, blk, 0, stream>>>(
      R2, dec_W + 2 * WN, dec_b + 2 * C_DIM, mean, scal, dec_be + C_DIM, R1,
      cs1, cs2, nullptr, nullptr, C_DIM);
  bn_stats2<<<s2Grid, blk, 0, stream>>>(cs1, cs2, dec_g + 2 * C_DIM, mean,
                                        scal);
  gemm_f32sp<0, 3, 1, 1><<<gemmGrid, blk, 0, stream>>>(
      R1, dec_W + 3 * WN, dec_b + 3 * C_DIM, mean, scal, dec_be + 2 * C_DIM,
      R2, cs1, cs2, nullptr, nullptr, C_DIM);
  bn_stats2<<<s2Grid, blk, 0, stream>>>(cs1, cs2, dec_g + 3 * C_DIM, mean,
                                        scal);
  // dec VQ head -> xrec
  gemm_f32sp<1, 3, 1, 0><<<gemmGrid, blk, 0, stream>>>(
      R2, dec_vW1, dec_vb1, mean, scal, dec_be + 3 * C_DIM, R1, nullptr,
      nullptr, nullptr, nullptr, C_DIM);
  gemm_f32sp<0, 3, 0, 0><<<gemmGrid, blk, 0, stream>>>(
      R1, dec_vW2, dec_vb2, nullptr, nullptr, nullptr, xrec, nullptr, nullptr,
      nullptr, nullptr, C_DIM);
}

// Round 6
// 1362.567 us; speedup vs baseline: 3.4024x; 1.1221x over previous
//
#include <hip/hip_runtime.h>

typedef unsigned int u32;
typedef unsigned short u16;
typedef unsigned long long u64;

typedef __attribute__((ext_vector_type(8))) short short8;     // MFMA A/B frag (8 bf16)
typedef __attribute__((ext_vector_type(4))) float f32x4;      // MFMA C/D frag
typedef __attribute__((ext_vector_type(8))) unsigned short u16x8;
typedef __attribute__((ext_vector_type(4))) unsigned short u16x4;

#define C_DIM 1024
#define B_ROWS 8192
#define N_EMB 8192
#define BN_EPS_C 1e-5f
#define KK 1024   // all GEMMs in this net have K = 1024

// ---------------- bf16 split helpers ---------------------------------------
__device__ __forceinline__ u16 f2bf_rne(float x) {
  u32 b = __float_as_uint(x);
  u32 r = b + 0x7fffu + ((b >> 16) & 1u);
  return (u16)(r >> 16);
}
__device__ __forceinline__ float bf2f(u16 h) {
  return __uint_as_float(((u32)h) << 16);
}

// ---------------- deterministic block reduce (256 threads) ----------------
__device__ __forceinline__ float block_reduce_sum_256(float v) {
#pragma unroll
  for (int off = 32; off > 0; off >>= 1) v += __shfl_xor(v, off, 64);
  __shared__ float sh[4];
  __syncthreads();
  const int lane = threadIdx.x & 63, w = threadIdx.x >> 6;
  if (lane == 0) sh[w] = v;
  __syncthreads();
  return (sh[0] + sh[1]) + (sh[2] + sh[3]);
}

__device__ __forceinline__ u64 shfl_xor_u64(u64 v, int m) {
  int lo = __shfl_xor((int)(u32)v, m, 64);
  int hi = __shfl_xor((int)(u32)(v >> 32), m, 64);
  return ((u64)(u32)hi << 32) | (u32)lo;
}

// ---------------- batched fp32 -> bf16 hi/lo split (4 segments) -------------
// Each block handles 1024 elements (256 threads x float4).
__global__ __launch_bounds__(256) void cvt4(
    const float* __restrict__ s0, u16* __restrict__ h0, u16* __restrict__ l0,
    int nb0, const float* __restrict__ s1, u16* __restrict__ h1,
    u16* __restrict__ l1, int nb1, const float* __restrict__ s2,
    u16* __restrict__ h2, u16* __restrict__ l2, int nb2,
    const float* __restrict__ s3, u16* __restrict__ h3, u16* __restrict__ l3) {
  int b = blockIdx.x;
  const float* s;
  u16 *h, *l;
  if (b < nb0) {
    s = s0; h = h0; l = l0;
  } else if (b < nb0 + nb1) {
    b -= nb0; s = s1; h = h1; l = l1;
  } else if (b < nb0 + nb1 + nb2) {
    b -= nb0 + nb1; s = s2; h = h2; l = l2;
  } else {
    b -= nb0 + nb1 + nb2; s = s3; h = h3; l = l3;
  }
  const int i = b * 256 + threadIdx.x;
  const float4 v = ((const float4*)s)[i];
  u16x4 hh, ll;
  hh.x = f2bf_rne(v.x); ll.x = f2bf_rne(v.x - bf2f(hh.x));
  hh.y = f2bf_rne(v.y); ll.y = f2bf_rne(v.y - bf2f(hh.y));
  hh.z = f2bf_rne(v.z); ll.z = f2bf_rne(v.z - bf2f(hh.z));
  hh.w = f2bf_rne(v.w); ll.w = f2bf_rne(v.w - bf2f(hh.w));
  ((u16x4*)h)[i] = hh;
  ((u16x4*)l)[i] = ll;
}

// ---------------- row L2 normalize, optional fp32 + hi/lo + best-init ------
template <int WF32>
__global__ __launch_bounds__(256) void l2norm_ext(const float* __restrict__ in,
                                                  float* __restrict__ outF,
                                                  u16* __restrict__ outH,
                                                  u16* __restrict__ outL,
                                                  float* __restrict__ ssq,
                                                  u64* __restrict__ binit) {
  const int row = blockIdx.x;
  const float4 v = ((const float4*)(in + (size_t)row * C_DIM))[threadIdx.x];
  float ss = v.x * v.x + v.y * v.y + v.z * v.z + v.w * v.w;
  ss = block_reduce_sum_256(ss);
  float nrm = sqrtf(ss);
  nrm = fmaxf(nrm, 1e-12f);
  float4 o;
  o.x = v.x / nrm; o.y = v.y / nrm; o.z = v.z / nrm; o.w = v.w / nrm;
  if (WF32) ((float4*)(outF + (size_t)row * C_DIM))[threadIdx.x] = o;
  u16x4 h, l;
  h.x = f2bf_rne(o.x); l.x = f2bf_rne(o.x - bf2f(h.x));
  h.y = f2bf_rne(o.y); l.y = f2bf_rne(o.y - bf2f(h.y));
  h.z = f2bf_rne(o.z); l.z = f2bf_rne(o.z - bf2f(h.z));
  h.w = f2bf_rne(o.w); l.w = f2bf_rne(o.w - bf2f(h.w));
  ((u16x4*)(outH + (size_t)row * C_DIM))[threadIdx.x] = h;
  ((u16x4*)(outL + (size_t)row * C_DIM))[threadIdx.x] = l;
  float s2 = o.x * o.x + o.y * o.y + o.z * o.z + o.w * o.w;
  s2 = block_reduce_sum_256(s2);
  if (threadIdx.x == 0) {
    ssq[row] = s2;
    if (binit) binit[row] = ~0ull;
  }
}

// ---------------- split-bf16 MFMA NT GEMM (r3 core + colsum epilogue) -------
// C = A@B^T from pre-split hi/lo operands.
// TERMS: 3 = hh+hl+lh, 4 = +ll (near-fp32, encoder).
// MODE:  0 = +bias -> fp32 out. 1 = +bias, tanh -> hi/lo out.
//        2 = distance argmin (bias = |e|^2, uses zz/best).
// CS:    1 = emit per-block column sums of out (cs1=sum, cs2=sum of squares).
template <int MODE, int TERMS, int CS>
__global__ __launch_bounds__(256, 2) void gemm_bf3(
    const u16* __restrict__ Ahg, const u16* __restrict__ Alg,
    const u16* __restrict__ Bhg, const u16* __restrict__ Blg,
    const float* __restrict__ bias, float* __restrict__ outF,
    u16* __restrict__ outH, u16* __restrict__ outL, float* __restrict__ cs1,
    float* __restrict__ cs2, const float* __restrict__ zz,
    u64* __restrict__ best, int N) {
  __shared__ __align__(16) u16 Ah[4096];
  __shared__ __align__(16) u16 Al[4096];
  __shared__ __align__(16) u16 Bh[4096];
  __shared__ __align__(16) u16 Bl[4096];
  __shared__ float csum[CS ? 4 * 64 * 2 : 1];
  const int tid = threadIdx.x;
  const int lane = tid & 63, w = tid >> 6;
  const int wr = w >> 1, wc = w & 1;
  const int m0 = blockIdx.y * 128, n0 = blockIdx.x * 128;
  const int r0 = tid >> 2, q0 = tid & 3;

  f32x4 acc[4][4];
#pragma unroll
  for (int i = 0; i < 4; ++i)
#pragma unroll
    for (int j = 0; j < 4; ++j) acc[i][j] = (f32x4){0.f, 0.f, 0.f, 0.f};

  for (int k0 = 0; k0 < KK; k0 += 32) {
    u16x8 va[2], vla[2], vb[2], vlb[2];
#pragma unroll
    for (int p = 0; p < 2; ++p) {
      const int r = p * 64 + r0;
      const size_t ga = (size_t)(m0 + r) * KK + k0 + q0 * 8;
      const size_t gb = (size_t)(n0 + r) * KK + k0 + q0 * 8;
      va[p] = *(const u16x8*)(Ahg + ga);
      vla[p] = *(const u16x8*)(Alg + ga);
      vb[p] = *(const u16x8*)(Bhg + gb);
      vlb[p] = *(const u16x8*)(Blg + gb);
    }
    __syncthreads();
#pragma unroll
    for (int p = 0; p < 2; ++p) {
      const int r = p * 64 + r0;
      const int off = r * 32 + ((q0 ^ ((r >> 1) & 3)) << 3);
      *(u16x8*)(Ah + off) = va[p];
      *(u16x8*)(Al + off) = vla[p];
      *(u16x8*)(Bh + off) = vb[p];
      *(u16x8*)(Bl + off) = vlb[p];
    }
    __syncthreads();

    short8 ah[4], al[4], bh[4], bl[4];
    const int q = lane >> 4;
#pragma unroll
    for (int t = 0; t < 4; ++t) {
      const int ra = wr * 64 + t * 16 + (lane & 15);
      const int oa = ra * 32 + ((q ^ ((ra >> 1) & 3)) << 3);
      ah[t] = *(const short8*)(Ah + oa);
      al[t] = *(const short8*)(Al + oa);
      const int rb = wc * 64 + t * 16 + (lane & 15);
      const int ob = rb * 32 + ((q ^ ((rb >> 1) & 3)) << 3);
      bh[t] = *(const short8*)(Bh + ob);
      bl[t] = *(const short8*)(Bl + ob);
    }
#pragma unroll
    for (int i = 0; i < 4; ++i)
#pragma unroll
      for (int j = 0; j < 4; ++j) {
        acc[i][j] = __builtin_amdgcn_mfma_f32_16x16x32_bf16(ah[i], bh[j],
                                                            acc[i][j], 0, 0, 0);
        acc[i][j] = __builtin_amdgcn_mfma_f32_16x16x32_bf16(ah[i], bl[j],
                                                            acc[i][j], 0, 0, 0);
        acc[i][j] = __builtin_amdgcn_mfma_f32_16x16x32_bf16(al[i], bh[j],
                                                            acc[i][j], 0, 0, 0);
        if (TERMS == 4)
          acc[i][j] = __builtin_amdgcn_mfma_f32_16x16x32_bf16(
              al[i], bl[j], acc[i][j], 0, 0, 0);
      }
  }

  // C/D layout: col = lane&15, row = (lane>>4)*4 + v   [m89-verified]
  const int rbase = m0 + wr * 64 + (lane >> 4) * 4;
  const int cbase = n0 + wc * 64 + (lane & 15);

  if (MODE == 2) {
    float sev[4];
#pragma unroll
    for (int j = 0; j < 4; ++j) sev[j] = bias[cbase + j * 16];
#pragma unroll
    for (int i = 0; i < 4; ++i)
#pragma unroll
      for (int v = 0; v < 4; ++v) {
        const int row = rbase + i * 16 + v;
        const float zr = zz[row];
        u64 bkey = ~0ull;
#pragma unroll
        for (int j = 0; j < 4; ++j) {
          const float d = (zr + sev[j]) - 2.0f * acc[i][j][v];
          const u32 fb = __float_as_uint(d);
          const u32 k32 = (fb & 0x80000000u) ? ~fb : (fb | 0x80000000u);
          const u64 key = ((u64)k32 << 32) | (u32)(cbase + j * 16);
          bkey = (key < bkey) ? key : bkey;
        }
#pragma unroll
        for (int mm = 1; mm < 16; mm <<= 1) {
          const u64 o = shfl_xor_u64(bkey, mm);
          bkey = (o < bkey) ? o : bkey;
        }
        if ((lane & 15) == 0) atomicMin(best + row, bkey);
      }
  } else {
    float bb[4];
#pragma unroll
    for (int j = 0; j < 4; ++j) bb[j] = bias[cbase + j * 16];
    float s[4] = {0.f, 0.f, 0.f, 0.f}, ss[4] = {0.f, 0.f, 0.f, 0.f};
#pragma unroll
    for (int i = 0; i < 4; ++i)
#pragma unroll
      for (int j = 0; j < 4; ++j)
#pragma unroll
        for (int v = 0; v < 4; ++v) {
          const int row = rbase + i * 16 + v;
          const int col = cbase + j * 16;
          float val = acc[i][j][v] + bb[j];
          if (MODE == 1) {
            val = tanhf(val);
            const u16 h = f2bf_rne(val);
            outH[(size_t)row * N + col] = h;
            outL[(size_t)row * N + col] = f2bf_rne(val - bf2f(h));
          } else {
            outF[(size_t)row * N + col] = val;
            if (CS) {
              s[j] += val;
              ss[j] += val * val;
            }
          }
        }
    if (CS) {
#pragma unroll
      for (int j = 0; j < 4; ++j) {
        s[j] += __shfl_xor(s[j], 16, 64);
        s[j] += __shfl_xor(s[j], 32, 64);
        ss[j] += __shfl_xor(ss[j], 16, 64);
        ss[j] += __shfl_xor(ss[j], 32, 64);
      }
      if (lane < 16) {
#pragma unroll
        for (int j = 0; j < 4; ++j) {
          csum[(w * 64 + j * 16 + lane) * 2 + 0] = s[j];
          csum[(w * 64 + j * 16 + lane) * 2 + 1] = ss[j];
        }
      }
      __syncthreads();
      if (tid < 128) {
        const int col = tid;
        const int wcc = col >> 6, idx = col & 63;
        const float S = csum[(wcc * 64 + idx) * 2 + 0] +
                        csum[((2 + wcc) * 64 + idx) * 2 + 0];
        const float SS = csum[(wcc * 64 + idx) * 2 + 1] +
                         csum[((2 + wcc) * 64 + idx) * 2 + 1];
        cs1[(size_t)blockIdx.y * C_DIM + n0 + col] = S;
        cs2[(size_t)blockIdx.y * C_DIM + n0 + col] = SS;
      }
    }
  }
}

// ---------------- BN finalize: fold 64 per-block partials -------------------
__global__ __launch_bounds__(256) void bn_stats2(const float* __restrict__ cs1,
                                                 const float* __restrict__ cs2,
                                                 const float* __restrict__ g,
                                                 float* __restrict__ mean,
                                                 float* __restrict__ scale) {
  const int c = blockIdx.x * 256 + threadIdx.x;
  float s = 0.f, ss = 0.f;
  for (int i = 0; i < 64; ++i) {
    s += cs1[i * C_DIM + c];
    ss += cs2[i * C_DIM + c];
  }
  const float m = s * (1.0f / 8192.0f);
  const float v = ss * (1.0f / 8192.0f) - m * m;  // biased var
  mean[c] = m;
  scale[c] = g[c] / sqrtf(v + BN_EPS_C);
}

// ---------------- BN apply + ReLU -> hi/lo ---------------------------------
__global__ __launch_bounds__(256) void bn_relu_cvt(
    const float* __restrict__ t, const float* __restrict__ mean,
    const float* __restrict__ scale, const float* __restrict__ be,
    u16* __restrict__ outH, u16* __restrict__ outL) {
  const int i = blockIdx.x * 256 + threadIdx.x;
  const int c4 = i & 255;
  const float4 v = ((const float4*)t)[i];
  const float4 m = ((const float4*)mean)[c4];
  const float4 sc = ((const float4*)scale)[c4];
  const float4 b = ((const float4*)be)[c4];
  float4 r;
  r.x = fmaxf((v.x - m.x) * sc.x + b.x, 0.f);
  r.y = fmaxf((v.y - m.y) * sc.y + b.y, 0.f);
  r.z = fmaxf((v.z - m.z) * sc.z + b.z, 0.f);
  r.w = fmaxf((v.w - m.w) * sc.w + b.w, 0.f);
  u16x4 h, l;
  h.x = f2bf_rne(r.x); l.x = f2bf_rne(r.x - bf2f(h.x));
  h.y = f2bf_rne(r.y); l.y = f2bf_rne(r.y - bf2f(h.y));
  h.z = f2bf_rne(r.z); l.z = f2bf_rne(r.z - bf2f(h.z));
  h.w = f2bf_rne(r.w); l.w = f2bf_rne(r.w - bf2f(h.w));
  ((u16x4*)outH)[i] = h;
  ((u16x4*)outL)[i] = l;
}

// ---------------- VQ gather (hi/lo e) -> zq hi/lo + row loss ----------------
__global__ __launch_bounds__(256) void gather_zq_cvt(
    const float* __restrict__ z, const u16* __restrict__ eh,
    const u16* __restrict__ el, const u64* __restrict__ best,
    u16* __restrict__ zqh, u16* __restrict__ zql, float* __restrict__ rowp) {
  const int row = blockIdx.x;
  const u32 idx = (u32)(best[row] & 0xffffffffu);
  const float4 zv = ((const float4*)(z + (size_t)row * C_DIM))[threadIdx.x];
  const u16x4 evh = ((const u16x4*)(eh + (size_t)idx * C_DIM))[threadIdx.x];
  const u16x4 evl = ((const u16x4*)(el + (size_t)idx * C_DIM))[threadIdx.x];
  float4 ev;
  ev.x = bf2f(evh.x) + bf2f(evl.x);
  ev.y = bf2f(evh.y) + bf2f(evl.y);
  ev.z = bf2f(evh.z) + bf2f(evl.z);
  ev.w = bf2f(evh.w) + bf2f(evl.w);
  float4 d, o;
  d.x = ev.x - zv.x; d.y = ev.y - zv.y; d.z = ev.z - zv.z; d.w = ev.w - zv.w;
  o.x = zv.x + d.x; o.y = zv.y + d.y; o.z = zv.z + d.z; o.w = zv.w + d.w;
  u16x4 h, l;
  h.x = f2bf_rne(o.x); l.x = f2bf_rne(o.x - bf2f(h.x));
  h.y = f2bf_rne(o.y); l.y = f2bf_rne(o.y - bf2f(h.y));
  h.z = f2bf_rne(o.z); l.z = f2bf_rne(o.z - bf2f(h.z));
  h.w = f2bf_rne(o.w); l.w = f2bf_rne(o.w - bf2f(h.w));
  ((u16x4*)(zqh + (size_t)row * C_DIM))[threadIdx.x] = h;
  ((u16x4*)(zql + (size_t)row * C_DIM))[threadIdx.x] = l;
  float ss = d.x * d.x + d.y * d.y + d.z * d.z + d.w * d.w;
  ss = block_reduce_sum_256(ss);
  if (threadIdx.x == 0) rowp[row] = ss;
}

__global__ __launch_bounds__(256) void embloss_fin(const float* __restrict__ rowp,
                                                   float* __restrict__ out) {
  float s = 0.f;
  for (int i = threadIdx.x; i < B_ROWS; i += 256) s += rowp[i];
  s = block_reduce_sum_256(s);
  if (threadIdx.x == 0) out[0] = s * (1.0f / (8192.0f * 1024.0f));
}

// ---------------- launch ----------------------------------------------------
extern "C" void kernel_launch(void* const* d_in, const int* in_sizes, int n_in,
                              void* d_out, int out_size, void* d_ws,
                              size_t ws_size, hipStream_t stream) {
  const float* x = (const float*)d_in[0];
  const float* enc_W = (const float*)d_in[1];
  const float* enc_b = (const float*)d_in[2];
  const float* enc_g = (const float*)d_in[3];
  const float* enc_be = (const float*)d_in[4];
  const float* enc_vW1 = (const float*)d_in[5];
  const float* enc_vb1 = (const float*)d_in[6];
  const float* enc_vW2 = (const float*)d_in[7];
  const float* enc_vb2 = (const float*)d_in[8];
  const float* dec_W = (const float*)d_in[9];
  const float* dec_b = (const float*)d_in[10];
  const float* dec_g = (const float*)d_in[11];
  const float* dec_be = (const float*)d_in[12];
  const float* dec_vW1 = (const float*)d_in[13];
  const float* dec_vb1 = (const float*)d_in[14];
  const float* dec_vW2 = (const float*)d_in[15];
  const float* dec_vb2 = (const float*)d_in[16];
  const float* cb = (const float*)d_in[17];

  const size_t NE = (size_t)B_ROWS * C_DIM;  // 8388608
  const size_t WN = (size_t)C_DIM * C_DIM;   // 1048576
  float* ws = (float*)d_ws;
  // Four NE-float regions, time-shared by liveness (~128.8 MB total):
  float* R1 = ws;        // h fp32 (enc+dec) | z fp32
  float* R2 = R1 + NE;   // x hi/lo | acts ping | zhi/zlo
  float* R3 = R2 + NE;   // acts pong | enc tanh | zq hi/lo
  float* R4 = R3 + NE;   // enc weight arena -> ehi/elo -> dec weight arena
  float* se = R4 + NE;
  float* zz = se + N_EMB;
  u64* best = (u64*)(zz + B_ROWS);
  float* cs1 = (float*)(best + B_ROWS);  // 64*1024
  float* cs2 = cs1 + 64 * C_DIM;         // 64*1024
  float* mean = cs2 + 64 * C_DIM;
  float* scal = mean + C_DIM;
  float* rowp = scal + C_DIM;

  // weight arena layout (u16 units within R4):
  //   [0,4WN) blkW hi | [4WN,8WN) blkW lo | [8WN,9WN) vW1 hi | [9WN,10WN) vW1 lo
  //   [10WN,11WN) vW2 hi | [11WN,12WN) vW2 lo      (25.2 MB of 33.5 MB)
  u16* wa = (u16*)R4;
  u16* ehi = (u16*)R4;   // after encoder: codebook hi/lo replace weights
  u16* elo = ehi + NE;
  u16* xh = (u16*)R2;    // x split
  u16* xl = xh + NE;
  u16* aH = (u16*)R2;    // act ping (same region as x: ping-pong below)
  u16* aL = aH + NE;
  u16* bH = (u16*)R3;    // act pong / tanh / zq
  u16* bL = bH + NE;
  u16* zhi = (u16*)R2;   // z hi/lo (acts dead by then)
  u16* zlo = zhi + NE;
  float* zf = R1;        // z fp32 (in-place l2norm of vW2 output)

  float* xrec = (float*)d_out;
  float* loss = xrec + NE;

  const dim3 blk(256);
  const dim3 gemmGrid(C_DIM / 128, B_ROWS / 128);  // (8, 64)
  const dim3 distGrid(N_EMB / 128, B_ROWS / 128);  // (64, 64)
  const dim3 s2Grid(C_DIM / 256);
  const dim3 brGrid(B_ROWS * C_DIM / 1024);

  // ---- one batched split: enc_W(4WN) + vW1 + vW2 + x ----
  cvt4<<<dim3(4096 + 1024 + 1024 + 8192), blk, 0, stream>>>(
      enc_W, wa, wa + 4 * WN, 4096, enc_vW1, wa + 8 * WN, wa + 9 * WN, 1024,
      enc_vW2, wa + 10 * WN, wa + 11 * WN, 1024, x, xh, xl);

  // ---- encoder: 4 x (GEMM+colsum -> stats2 -> bn_relu_cvt) ----
  gemm_bf3<0, 4, 1><<<gemmGrid, blk, 0, stream>>>(
      xh, xl, wa, wa + 4 * WN, enc_b, R1, nullptr, nullptr, cs1, cs2, nullptr,
      nullptr, C_DIM);
  bn_stats2<<<s2Grid, blk, 0, stream>>>(cs1, cs2, enc_g, mean, scal);
  bn_relu_cvt<<<brGrid, blk, 0, stream>>>(R1, mean, scal, enc_be, bH, bL);

  gemm_bf3<0, 4, 1><<<gemmGrid, blk, 0, stream>>>(
      bH, bL, wa + WN, wa + 5 * WN, enc_b + C_DIM, R1, nullptr, nullptr, cs1,
      cs2, nullptr, nullptr, C_DIM);
  bn_stats2<<<s2Grid, blk, 0, stream>>>(cs1, cs2, enc_g + C_DIM, mean, scal);
  bn_relu_cvt<<<brGrid, blk, 0, stream>>>(R1, mean, scal, enc_be + C_DIM, aH,
                                          aL);

  gemm_bf3<0, 4, 1><<<gemmGrid, blk, 0, stream>>>(
      aH, aL, wa + 2 * WN, wa + 6 * WN, enc_b + 2 * C_DIM, R1, nullptr,
      nullptr, cs1, cs2, nullptr, nullptr, C_DIM);
  bn_stats2<<<s2Grid, blk, 0, stream>>>(cs1, cs2, enc_g + 2 * C_DIM, mean,
                                        scal);
  bn_relu_cvt<<<brGrid, blk, 0, stream>>>(R1, mean, scal, enc_be + 2 * C_DIM,
                                          bH, bL);

  gemm_bf3<0, 4, 1><<<gemmGrid, blk, 0, stream>>>(
      bH, bL, wa + 3 * WN, wa + 7 * WN, enc_b + 3 * C_DIM, R1, nullptr,
      nullptr, cs1, cs2, nullptr, nullptr, C_DIM);
  bn_stats2<<<s2Grid, blk, 0, stream>>>(cs1, cs2, enc_g + 3 * C_DIM, mean,
                                        scal);
  bn_relu_cvt<<<brGrid, blk, 0, stream>>>(R1, mean, scal, enc_be + 3 * C_DIM,
                                          aH, aL);

  // enc VQ head: tanh -> bH/bL, then vW2 -> z fp32 (R1)
  gemm_bf3<1, 4, 0><<<gemmGrid, blk, 0, stream>>>(
      aH, aL, wa + 8 * WN, wa + 9 * WN, enc_vb1, nullptr, bH, bL, nullptr,
      nullptr, nullptr, nullptr, C_DIM);
  gemm_bf3<0, 4, 0><<<gemmGrid, blk, 0, stream>>>(
      bH, bL, wa + 10 * WN, wa + 11 * WN, enc_vb2, zf, nullptr, nullptr,
      nullptr, nullptr, nullptr, nullptr, C_DIM);

  // ---- quantizer ----  (enc weights dead -> R4 becomes codebook hi/lo)
  l2norm_ext<0><<<N_EMB, blk, 0, stream>>>(cb, nullptr, ehi, elo, se, nullptr);
  l2norm_ext<1><<<B_ROWS, blk, 0, stream>>>(zf, zf, zhi, zlo, zz, best);
  gemm_bf3<2, 3, 0><<<distGrid, blk, 0, stream>>>(
      zhi, zlo, ehi, elo, se, nullptr, nullptr, nullptr, nullptr, nullptr, zz,
      best, N_EMB);
  gather_zq_cvt<<<B_ROWS, blk, 0, stream>>>(zf, ehi, elo, best, bH, bL, rowp);
  embloss_fin<<<1, blk, 0, stream>>>(rowp, loss);

  // ---- decoder ----  (ehi/elo dead -> R4 becomes decoder weight arena)
  cvt4<<<dim3(4096 + 1024 + 1024), blk, 0, stream>>>(
      dec_W, wa, wa + 4 * WN, 4096, dec_vW1, wa + 8 * WN, wa + 9 * WN, 1024,
      dec_vW2, wa + 10 * WN, wa + 11 * WN, 1024, nullptr, nullptr, nullptr);

  gemm_bf3<0, 3, 1><<<gemmGrid, blk, 0, stream>>>(
      bH, bL, wa, wa + 4 * WN, dec_b, R1, nullptr, nullptr, cs1, cs2, nullptr,
      nullptr, C_DIM);
  bn_stats2<<<s2Grid, blk, 0, stream>>>(cs1, cs2, dec_g, mean, scal);
  bn_relu_cvt<<<brGrid, blk, 0, stream>>>(R1, mean, scal, dec_be, aH, aL);

  gemm_bf3<0, 3, 1><<<gemmGrid, blk, 0, stream>>>(
      aH, aL, wa + WN, wa + 5 * WN, dec_b + C_DIM, R1, nullptr, nullptr, cs1,
      cs2, nullptr, nullptr, C_DIM);
  bn_stats2<<<s2Grid, blk, 0, stream>>>(cs1, cs2, dec_g + C_DIM, mean, scal);
  bn_relu_cvt<<<brGrid, blk, 0, stream>>>(R1, mean, scal, dec_be + C_DIM, bH,
                                          bL);

  gemm_bf3<0, 3, 1><<<gemmGrid, blk, 0, stream>>>(
      bH, bL, wa + 2 * WN, wa + 6 * WN, dec_b + 2 * C_DIM, R1, nullptr,
      nullptr, cs1, cs2, nullptr, nullptr, C_DIM);
  bn_stats2<<<s2Grid, blk, 0, stream>>>(cs1, cs2, dec_g + 2 * C_DIM, mean,
                                        scal);
  bn_relu_cvt<<<brGrid, blk, 0, stream>>>(R1, mean, scal, dec_be + 2 * C_DIM,
                                          aH, aL);

  gemm_bf3<0, 3, 1><<<gemmGrid, blk, 0, stream>>>(
      aH, aL, wa + 3 * WN, wa + 7 * WN, dec_b + 3 * C_DIM, R1, nullptr,
      nullptr, cs1, cs2, nullptr, nullptr, C_DIM);
  bn_stats2<<<s2Grid, blk, 0, stream>>>(cs1, cs2, dec_g + 3 * C_DIM, mean,
                                        scal);
  bn_relu_cvt<<<brGrid, blk, 0, stream>>>(R1, mean, scal, dec_be + 3 * C_DIM,
                                          bH, bL);

  // dec VQ head -> xrec
  gemm_bf3<1, 3, 0><<<gemmGrid, blk, 0, stream>>>(
      bH, bL, wa + 8 * WN, wa + 9 * WN, dec_vb1, nullptr, aH, aL, nullptr,
      nullptr, nullptr, nullptr, C_DIM);
  gemm_bf3<0, 3, 0><<<gemmGrid, blk, 0, stream>>>(
      aH, aL, wa + 10 * WN, wa + 11 * WN, dec_vb2, xrec, nullptr, nullptr,
      nullptr, nullptr, nullptr, nullptr, C_DIM);
}